// Round 2
// baseline (581.853 us; speedup 1.0000x reference)
//
#include <hip/hip_runtime.h>
#include <hip/hip_bf16.h>

// ---- degrees: deg_gcn[c] += w_e ; deg_dmon[c] += 1 --------------------------
__global__ void k_deg(const int* __restrict__ ei, const float* __restrict__ ew,
                      float* __restrict__ deg_gcn, float* __restrict__ deg_dmon, int E) {
    int e = blockIdx.x * blockDim.x + threadIdx.x;
    if (e < E) {
        int c = ei[E + e];
        atomicAdd(deg_gcn + c, ew[e]);
        atomicAdd(deg_dmon + c, 1.0f);
    }
}

// ---- dis[i] = rsqrt(deg + 1) (self-loop weight 1; deg+1 > 0 always) ---------
__global__ void k_dis(float* __restrict__ deg_gcn, int N) {
    int i = blockIdx.x * blockDim.x + threadIdx.x;
    if (i < N) deg_gcn[i] = rsqrtf(deg_gcn[i] + 1.0f);
}

// ---- xw = x @ W1  [N,128]x[128,64] -> f32 -----------------------------------
__global__ void k_xw(const float* __restrict__ x, const float* __restrict__ W1,
                     float* __restrict__ xw, int N) {
    __shared__ float w1l[128 * 64];
    for (int t = threadIdx.x; t < 128 * 64; t += blockDim.x) w1l[t] = W1[t];
    __syncthreads();
    int lane = threadIdx.x & 63;
    int wid  = threadIdx.x >> 6;
    int nw   = (blockDim.x >> 6) * gridDim.x;
    for (int row = blockIdx.x * (blockDim.x >> 6) + wid; row < N; row += nw) {
        float xlo = x[row * 128 + lane];
        float xhi = x[row * 128 + 64 + lane];
        float acc = 0.f;
#pragma unroll
        for (int k = 0; k < 64; ++k)
            acc = fmaf(__shfl(xlo, k), w1l[k * 64 + lane], acc);
#pragma unroll
        for (int k = 0; k < 64; ++k)
            acc = fmaf(__shfl(xhi, k), w1l[(64 + k) * 64 + lane], acc);
        xw[row * 64 + lane] = acc;
    }
}

// ---- GCN edge scatter: hacc[c,:] += xw[r,:] * (dis[r]*w*dis[c]) -------------
__global__ void k_scatter(const int* __restrict__ ei, const float* __restrict__ ew,
                          const float* __restrict__ dis, const float* __restrict__ xw,
                          float* __restrict__ hacc, int E) {
    int lane = threadIdx.x & 63;
    int wid  = blockIdx.x * (blockDim.x >> 6) + (threadIdx.x >> 6);
    int nw   = (blockDim.x >> 6) * gridDim.x;
    for (int e = wid; e < E; e += nw) {
        int r = ei[e], c = ei[E + e];
        float norm = dis[r] * ew[e] * dis[c];
        atomicAdd(&hacc[c * 64 + lane], xw[r * 64 + lane] * norm);
    }
}

// ---- h = relu(hacc + xw*dis^2 (self loop) + b1) -----------------------------
__global__ void k_hfin(const float* __restrict__ xw, const float* __restrict__ dis,
                       const float* __restrict__ b1, float* __restrict__ hacc, int total) {
    int idx = blockIdx.x * blockDim.x + threadIdx.x;
    if (idx < total) {
        int i = idx >> 6, j = idx & 63;
        float d = dis[i];
        float v = hacc[idx] + xw[idx] * d * d + b1[j];
        hacc[idx] = v > 0.f ? v : 0.f;
    }
}

// ---- s = softmax((h@Wm1+bm1)@Wm2+bm2) written straight into d_out (f32) -----
__global__ void k_mlp(const float* __restrict__ h,
                      const float* __restrict__ Wm1, const float* __restrict__ bm1,
                      const float* __restrict__ Wm2, const float* __restrict__ bm2,
                      float* __restrict__ s, int N) {
    __shared__ float w1l[4096], w2l[4096], b1l[64], b2l[64];
    for (int t = threadIdx.x; t < 4096; t += blockDim.x) {
        w1l[t] = Wm1[t];
        w2l[t] = Wm2[t];
    }
    if (threadIdx.x < 64) {
        b1l[threadIdx.x] = bm1[threadIdx.x];
        b2l[threadIdx.x] = bm2[threadIdx.x];
    }
    __syncthreads();
    int lane = threadIdx.x & 63;
    int wid  = threadIdx.x >> 6;
    int nw   = (blockDim.x >> 6) * gridDim.x;
    for (int row = blockIdx.x * (blockDim.x >> 6) + wid; row < N; row += nw) {
        float hj = h[row * 64 + lane];
        float t = b1l[lane];
#pragma unroll
        for (int k = 0; k < 64; ++k) t = fmaf(__shfl(hj, k), w1l[k * 64 + lane], t);
        float lg = b2l[lane];
#pragma unroll
        for (int k = 0; k < 64; ++k) lg = fmaf(__shfl(t, k), w2l[k * 64 + lane], lg);
        float mx = lg;
#pragma unroll
        for (int o = 32; o > 0; o >>= 1) mx = fmaxf(mx, __shfl_xor(mx, o));
        float ex = __expf(lg - mx);
        float sm = ex;
#pragma unroll
        for (int o = 32; o > 0; o >>= 1) sm += __shfl_xor(sm, o);
        s[row * 64 + lane] = ex / sm;
    }
}

// ---- row reductions: ss = s^T s, cs = colsum(s), ca = s^T deg ---------------
__global__ void k_rowred(const float* __restrict__ s, const float* __restrict__ degd,
                         float* __restrict__ ssg, float* __restrict__ cag,
                         float* __restrict__ csg, int N) {
    __shared__ float ssl[4096];
    for (int t = threadIdx.x; t < 4096; t += blockDim.x) ssl[t] = 0.f;
    __syncthreads();
    int lane = threadIdx.x & 63;
    int wid  = threadIdx.x >> 6;
    int nw   = (blockDim.x >> 6) * gridDim.x;
    float ssacc[64];
#pragma unroll
    for (int a = 0; a < 64; ++a) ssacc[a] = 0.f;
    float csj = 0.f, caj = 0.f;
    for (int row = blockIdx.x * (blockDim.x >> 6) + wid; row < N; row += nw) {
        float sj = s[row * 64 + lane];
        float d = degd[row];
        csj += sj;
        caj += sj * d;
#pragma unroll
        for (int a = 0; a < 64; ++a) ssacc[a] = fmaf(__shfl(sj, a), sj, ssacc[a]);
    }
#pragma unroll
    for (int a = 0; a < 64; ++a) atomicAdd(&ssl[a * 64 + lane], ssacc[a]);
    atomicAdd(&csg[lane], csj);
    atomicAdd(&cag[lane], caj);
    __syncthreads();
    for (int t = threadIdx.x; t < 4096; t += blockDim.x) atomicAdd(&ssg[t], ssl[t]);
}

// ---- trace(out_adj) = sum over edges of dot(s[r], s[c]) ---------------------
__global__ void k_trace(const int* __restrict__ ei, const float* __restrict__ s,
                        float* __restrict__ traceg, int E) {
    int lane = threadIdx.x & 63;
    int wid  = blockIdx.x * (blockDim.x >> 6) + (threadIdx.x >> 6);
    int nw   = (blockDim.x >> 6) * gridDim.x;
    float acc = 0.f;
    for (int e = wid; e < E; e += nw) {
        int r = ei[e], c = ei[E + e];
        acc += s[r * 64 + lane] * s[c * 64 + lane];
    }
#pragma unroll
    for (int o = 32; o > 0; o >>= 1) acc += __shfl_xor(acc, o);
    __shared__ float bsum;
    if (threadIdx.x == 0) bsum = 0.f;
    __syncthreads();
    if (lane == 0) atomicAdd(&bsum, acc);
    __syncthreads();
    if (threadIdx.x == 0) atomicAdd(traceg, bsum);
}

// ---- finalize: spectral + ortho + cluster loss ------------------------------
__global__ void k_final(const float* __restrict__ ssg, const float* __restrict__ cag,
                        const float* __restrict__ csg, const float* __restrict__ traceg,
                        float Ef, float Nf, float* __restrict__ out) {
    __shared__ float red[256];
    int tid = threadIdx.x;

    float a = 0.f;
    for (int t = tid; t < 4096; t += 256) { float v = ssg[t]; a += v * v; }
    red[tid] = a; __syncthreads();
    for (int o = 128; o > 0; o >>= 1) { if (tid < o) red[tid] += red[tid + o]; __syncthreads(); }
    float ss_sumsq = red[0]; __syncthreads();

    a = (tid < 64) ? ssg[tid * 64 + tid] : 0.f;
    red[tid] = a; __syncthreads();
    for (int o = 128; o > 0; o >>= 1) { if (tid < o) red[tid] += red[tid + o]; __syncthreads(); }
    float tr_ss = red[0]; __syncthreads();

    a = (tid < 64) ? cag[tid] * cag[tid] : 0.f;
    red[tid] = a; __syncthreads();
    for (int o = 128; o > 0; o >>= 1) { if (tid < o) red[tid] += red[tid + o]; __syncthreads(); }
    float ca_ss = red[0]; __syncthreads();

    a = (tid < 64) ? csg[tid] * csg[tid] : 0.f;
    red[tid] = a; __syncthreads();
    for (int o = 128; o > 0; o >>= 1) { if (tid < o) red[tid] += red[tid + o]; __syncthreads(); }
    float cs_ss = red[0];

    if (tid == 0) {
        // m = deg.sum()/2 = E/2  =>  2m = E
        float spec = -(traceg[0] - ca_ss / Ef) / Ef;
        float ss_fro = sqrtf(ss_sumsq);
        // ||ss/fro - I/8||_F^2 = (1) - tr(ss)/(4*fro) + (1)
        float ortho = sqrtf(fmaxf(2.f - tr_ss / (4.f * ss_fro), 0.f));
        float clus = sqrtf(cs_ss) / Nf * 8.f - 1.f;
        out[0] = spec + ortho + clus;
    }
}

extern "C" void kernel_launch(void* const* d_in, const int* in_sizes, int n_in,
                              void* d_out, int out_size, void* d_ws, size_t ws_size,
                              hipStream_t stream) {
    const float* x   = (const float*)d_in[0];
    const int*   ei  = (const int*)d_in[1];
    const float* ew  = (const float*)d_in[2];
    const float* W1  = (const float*)d_in[3];
    const float* b1  = (const float*)d_in[4];
    const float* Wm1 = (const float*)d_in[5];
    const float* bm1 = (const float*)d_in[6];
    const float* Wm2 = (const float*)d_in[7];
    const float* bm2 = (const float*)d_in[8];
    float* out = (float*)d_out;

    const int N = in_sizes[0] / 128;   // 16384
    const int E = in_sizes[2];         // 524288

    float* ws   = (float*)d_ws;
    float* xw   = ws;                          // N*64
    float* hacc = ws + (size_t)N * 64;         // N*64
    float* dis  = ws + (size_t)2 * N * 64;     // N  (deg_gcn -> dis in place)
    float* degd = dis + N;                     // N
    float* ssg  = degd + N;                    // 4096
    float* cag  = ssg + 4096;                  // 64
    float* csg  = cag + 64;                    // 64
    float* trg  = csg + 64;                    // 1
    float* sbuf = out;                         // s lives in d_out (f32 output 0)

    size_t zbytes = ((size_t)2 * N * 64 + 2 * (size_t)N + 4096 + 64 + 64 + 1) * sizeof(float);
    hipMemsetAsync(d_ws, 0, zbytes, stream);

    k_deg<<<(E + 255) / 256, 256, 0, stream>>>(ei, ew, dis, degd, E);
    k_dis<<<(N + 255) / 256, 256, 0, stream>>>(dis, N);
    k_xw<<<512, 256, 0, stream>>>(x, W1, xw, N);
    k_scatter<<<1024, 256, 0, stream>>>(ei, ew, dis, xw, hacc, E);
    k_hfin<<<(N * 64 + 255) / 256, 256, 0, stream>>>(xw, dis, b1, hacc, N * 64);
    k_mlp<<<512, 256, 0, stream>>>(hacc, Wm1, bm1, Wm2, bm2, sbuf, N);
    k_rowred<<<128, 256, 0, stream>>>(sbuf, degd, ssg, cag, csg, N);
    k_trace<<<1024, 256, 0, stream>>>(ei, sbuf, trg, E);
    k_final<<<1, 256, 0, stream>>>(ssg, cag, csg, trg, (float)E, (float)N, out + (size_t)N * 64);
}

// Round 3
// 513.850 us; speedup vs baseline: 1.1323x; 1.1323x over previous
//
#include <hip/hip_runtime.h>
#include <hip/hip_bf16.h>

// ---- degrees: deg[c] += w_e (gcn) ; cnt[c] += 1 (dmon + bucket sizes) -------
__global__ void k_deg(const int* __restrict__ ei, const float* __restrict__ ew,
                      float* __restrict__ deg, int* __restrict__ cnt, int E) {
    int e = blockIdx.x * blockDim.x + threadIdx.x;
    if (e < E) {
        int c = ei[E + e];
        atomicAdd(deg + c, ew[e]);
        atomicAdd(cnt + c, 1);
    }
}

// ---- exclusive prefix sum of cnt -> offs[0..N]; fused dis = rsqrt(deg+1) ----
__global__ void k_scan(const int* __restrict__ cnt, int* __restrict__ offs,
                       float* __restrict__ deg, int N) {
    __shared__ int part[1024];
    int tid = threadIdx.x;
    int C = (N + 1023) / 1024;   // 16 for N=16384
    int base = tid * C;
    int loc[16];
    int sum = 0;
#pragma unroll
    for (int i = 0; i < 16; ++i) {
        if (i < C) {
            int idx = base + i;
            loc[i] = sum;
            sum += (idx < N) ? cnt[idx] : 0;
        }
    }
    part[tid] = sum;
    __syncthreads();
    for (int o = 1; o < 1024; o <<= 1) {
        int t = (tid >= o) ? part[tid - o] : 0;
        __syncthreads();
        part[tid] += t;
        __syncthreads();
    }
    int excl = part[tid] - sum;
#pragma unroll
    for (int i = 0; i < 16; ++i) {
        if (i < C) {
            int idx = base + i;
            if (idx < N) offs[idx] = excl + loc[i];
        }
    }
    if (tid == 1023) offs[N] = part[tid];
    for (int i = tid; i < N; i += 1024) deg[i] = rsqrtf(deg[i] + 1.0f);
}

// ---- xw = x @ W1  [N,128]x[128,64] -> f32 -----------------------------------
__global__ void k_xw(const float* __restrict__ x, const float* __restrict__ W1,
                     float* __restrict__ xw, int N) {
    __shared__ float w1l[128 * 64];
    for (int t = threadIdx.x; t < 128 * 64; t += blockDim.x) w1l[t] = W1[t];
    __syncthreads();
    int lane = threadIdx.x & 63;
    int wid  = threadIdx.x >> 6;
    int nw   = (blockDim.x >> 6) * gridDim.x;
    for (int row = blockIdx.x * (blockDim.x >> 6) + wid; row < N; row += nw) {
        float xlo = x[row * 128 + lane];
        float xhi = x[row * 128 + 64 + lane];
        float acc = 0.f;
#pragma unroll
        for (int k = 0; k < 64; ++k)
            acc = fmaf(__shfl(xlo, k), w1l[k * 64 + lane], acc);
#pragma unroll
        for (int k = 0; k < 64; ++k)
            acc = fmaf(__shfl(xhi, k), w1l[(64 + k) * 64 + lane], acc);
        xw[row * 64 + lane] = acc;
    }
}

// ---- counting-sort edges into per-target buckets: (r, norm) -----------------
__global__ void k_bucket(const int* __restrict__ ei, const float* __restrict__ ew,
                         const float* __restrict__ dis, const int* __restrict__ offs,
                         int* __restrict__ cursor, int2* __restrict__ bucket, int E) {
    int e = blockIdx.x * blockDim.x + threadIdx.x;
    if (e < E) {
        int r = ei[e], c = ei[E + e];
        float norm = dis[r] * ew[e] * dis[c];
        int pos = offs[c] + atomicAdd(&cursor[c], 1);
        bucket[pos] = make_int2(r, __float_as_int(norm));
    }
}

// ---- per-row gather: h[c,:] = relu(sum_e xw[r_e,:]*norm_e + xw[c,:]*dis^2 + b1)
__global__ void k_gather(const int* __restrict__ offs, const int2* __restrict__ bucket,
                         const float* __restrict__ xw, const float* __restrict__ dis,
                         const float* __restrict__ b1, float* __restrict__ h, int N) {
    int lane = threadIdx.x & 63;
    int wid  = blockIdx.x * (blockDim.x >> 6) + (threadIdx.x >> 6);
    int nw   = (blockDim.x >> 6) * gridDim.x;
    for (int c = wid; c < N; c += nw) {
        int beg = offs[c], end = offs[c + 1];
        float d = dis[c];
        float acc = xw[c * 64 + lane] * d * d;   // self-loop (weight 1)
        for (int i = beg; i < end; i += 64) {
            int nloc = min(64, end - i);
            int2 b = (i + lane < end) ? bucket[i + lane] : make_int2(0, 0);
            int rv = b.x;
            float nv = __int_as_float(b.y);
            for (int j = 0; j < nloc; ++j) {
                int r = __shfl(rv, j);
                float nm = __shfl(nv, j);
                acc = fmaf(xw[r * 64 + lane], nm, acc);
            }
        }
        float v = acc + b1[lane];
        h[c * 64 + lane] = v > 0.f ? v : 0.f;
    }
}

// ---- s = softmax((h@Wm1+bm1)@Wm2+bm2) written straight into d_out (f32) -----
__global__ void k_mlp(const float* __restrict__ h,
                      const float* __restrict__ Wm1, const float* __restrict__ bm1,
                      const float* __restrict__ Wm2, const float* __restrict__ bm2,
                      float* __restrict__ s, int N) {
    __shared__ float w1l[4096], w2l[4096], b1l[64], b2l[64];
    for (int t = threadIdx.x; t < 4096; t += blockDim.x) {
        w1l[t] = Wm1[t];
        w2l[t] = Wm2[t];
    }
    if (threadIdx.x < 64) {
        b1l[threadIdx.x] = bm1[threadIdx.x];
        b2l[threadIdx.x] = bm2[threadIdx.x];
    }
    __syncthreads();
    int lane = threadIdx.x & 63;
    int wid  = threadIdx.x >> 6;
    int nw   = (blockDim.x >> 6) * gridDim.x;
    for (int row = blockIdx.x * (blockDim.x >> 6) + wid; row < N; row += nw) {
        float hj = h[row * 64 + lane];
        float t = b1l[lane];
#pragma unroll
        for (int k = 0; k < 64; ++k) t = fmaf(__shfl(hj, k), w1l[k * 64 + lane], t);
        float lg = b2l[lane];
#pragma unroll
        for (int k = 0; k < 64; ++k) lg = fmaf(__shfl(t, k), w2l[k * 64 + lane], lg);
        float mx = lg;
#pragma unroll
        for (int o = 32; o > 0; o >>= 1) mx = fmaxf(mx, __shfl_xor(mx, o));
        float ex = __expf(lg - mx);
        float sm = ex;
#pragma unroll
        for (int o = 32; o > 0; o >>= 1) sm += __shfl_xor(sm, o);
        s[row * 64 + lane] = ex / sm;
    }
}

// ---- row reductions: ss = s^T s, cs = colsum(s), ca = s^T deg ---------------
__global__ void k_rowred(const float* __restrict__ s, const int* __restrict__ cnt,
                         float* __restrict__ ssg, float* __restrict__ cag,
                         float* __restrict__ csg, int N) {
    __shared__ float ssl[4096];
    for (int t = threadIdx.x; t < 4096; t += blockDim.x) ssl[t] = 0.f;
    __syncthreads();
    int lane = threadIdx.x & 63;
    int wid  = threadIdx.x >> 6;
    int nw   = (blockDim.x >> 6) * gridDim.x;
    float ssacc[64];
#pragma unroll
    for (int a = 0; a < 64; ++a) ssacc[a] = 0.f;
    float csj = 0.f, caj = 0.f;
    for (int row = blockIdx.x * (blockDim.x >> 6) + wid; row < N; row += nw) {
        float sj = s[row * 64 + lane];
        float d = (float)cnt[row];
        csj += sj;
        caj += sj * d;
#pragma unroll
        for (int a = 0; a < 64; ++a) ssacc[a] = fmaf(__shfl(sj, a), sj, ssacc[a]);
    }
#pragma unroll
    for (int a = 0; a < 64; ++a) atomicAdd(&ssl[a * 64 + lane], ssacc[a]);
    atomicAdd(&csg[lane], csj);
    atomicAdd(&cag[lane], caj);
    __syncthreads();
    for (int t = threadIdx.x; t < 4096; t += blockDim.x) atomicAdd(&ssg[t], ssl[t]);
}

// ---- trace via buckets: per row c, vsum = sum_e s[r_e,:]; tr += dot(vsum, s[c,:])
__global__ void k_trace2(const int* __restrict__ offs, const int2* __restrict__ bucket,
                         const float* __restrict__ s, float* __restrict__ traceg, int N) {
    int lane = threadIdx.x & 63;
    int wid  = blockIdx.x * (blockDim.x >> 6) + (threadIdx.x >> 6);
    int nw   = (blockDim.x >> 6) * gridDim.x;
    float acc = 0.f;
    for (int c = wid; c < N; c += nw) {
        int beg = offs[c], end = offs[c + 1];
        float vsum = 0.f;
        for (int i = beg; i < end; i += 64) {
            int nloc = min(64, end - i);
            int rvv = (i + lane < end) ? bucket[i + lane].x : 0;
            for (int j = 0; j < nloc; ++j) {
                int r = __shfl(rvv, j);
                vsum += s[r * 64 + lane];
            }
        }
        acc = fmaf(vsum, s[c * 64 + lane], acc);
    }
#pragma unroll
    for (int o = 32; o > 0; o >>= 1) acc += __shfl_xor(acc, o);
    __shared__ float bsum;
    if (threadIdx.x == 0) bsum = 0.f;
    __syncthreads();
    if (lane == 0) atomicAdd(&bsum, acc);
    __syncthreads();
    if (threadIdx.x == 0) atomicAdd(traceg, bsum);
}

// ---- finalize: spectral + ortho + cluster loss ------------------------------
__global__ void k_final(const float* __restrict__ ssg, const float* __restrict__ cag,
                        const float* __restrict__ csg, const float* __restrict__ traceg,
                        float Ef, float Nf, float* __restrict__ out) {
    __shared__ float red[256];
    int tid = threadIdx.x;

    float a = 0.f;
    for (int t = tid; t < 4096; t += 256) { float v = ssg[t]; a += v * v; }
    red[tid] = a; __syncthreads();
    for (int o = 128; o > 0; o >>= 1) { if (tid < o) red[tid] += red[tid + o]; __syncthreads(); }
    float ss_sumsq = red[0]; __syncthreads();

    a = (tid < 64) ? ssg[tid * 64 + tid] : 0.f;
    red[tid] = a; __syncthreads();
    for (int o = 128; o > 0; o >>= 1) { if (tid < o) red[tid] += red[tid + o]; __syncthreads(); }
    float tr_ss = red[0]; __syncthreads();

    a = (tid < 64) ? cag[tid] * cag[tid] : 0.f;
    red[tid] = a; __syncthreads();
    for (int o = 128; o > 0; o >>= 1) { if (tid < o) red[tid] += red[tid + o]; __syncthreads(); }
    float ca_ss = red[0]; __syncthreads();

    a = (tid < 64) ? csg[tid] * csg[tid] : 0.f;
    red[tid] = a; __syncthreads();
    for (int o = 128; o > 0; o >>= 1) { if (tid < o) red[tid] += red[tid + o]; __syncthreads(); }
    float cs_ss = red[0];

    if (tid == 0) {
        // 2m = deg.sum() = E
        float spec = -(traceg[0] - ca_ss / Ef) / Ef;
        float ss_fro = sqrtf(ss_sumsq);
        // ||ss/fro - I/8||_F^2 = 1 - tr(ss)/(4*fro) + 1
        float ortho = sqrtf(fmaxf(2.f - tr_ss / (4.f * ss_fro), 0.f));
        float clus = sqrtf(cs_ss) / Nf * 8.f - 1.f;
        out[0] = spec + ortho + clus;
    }
}

extern "C" void kernel_launch(void* const* d_in, const int* in_sizes, int n_in,
                              void* d_out, int out_size, void* d_ws, size_t ws_size,
                              hipStream_t stream) {
    const float* x   = (const float*)d_in[0];
    const int*   ei  = (const int*)d_in[1];
    const float* ew  = (const float*)d_in[2];
    const float* W1  = (const float*)d_in[3];
    const float* b1  = (const float*)d_in[4];
    const float* Wm1 = (const float*)d_in[5];
    const float* bm1 = (const float*)d_in[6];
    const float* Wm2 = (const float*)d_in[7];
    const float* bm2 = (const float*)d_in[8];
    float* out = (float*)d_out;

    const int N = in_sizes[0] / 128;   // 16384
    const int E = in_sizes[2];         // 524288

    float* ws = (float*)d_ws;
    // --- zeroed region ---
    float* deg    = ws;                       // N  (-> dis in place after k_scan)
    int*   cnt    = (int*)(ws + N);           // N
    int*   cursor = cnt + N;                  // N
    float* ssg    = (float*)(cursor + N);     // 4096
    float* cag    = ssg + 4096;               // 64
    float* csg    = cag + 64;                 // 64
    float* trg    = csg + 64;                 // 1
    // --- uninitialized region ---
    float* xw = trg + 1;                      // N*64
    float* h  = xw + (size_t)N * 64;          // N*64
    size_t foff = (size_t)(h + (size_t)N * 64 - ws);
    foff = (foff + 1) & ~(size_t)1;           // 8B-align for int2
    int2* bucket = (int2*)(ws + foff);        // E int2
    int*  offs   = (int*)(bucket + E);        // N+1
    float* sbuf  = out;                       // s lives in d_out (f32 output 0)

    size_t zbytes = ((size_t)3 * N + 4096 + 64 + 64 + 1) * sizeof(float);
    hipMemsetAsync(d_ws, 0, zbytes, stream);

    k_deg<<<(E + 255) / 256, 256, 0, stream>>>(ei, ew, deg, cnt, E);
    k_scan<<<1, 1024, 0, stream>>>(cnt, offs, deg, N);
    k_xw<<<512, 256, 0, stream>>>(x, W1, xw, N);
    k_bucket<<<(E + 255) / 256, 256, 0, stream>>>(ei, ew, deg, offs, cursor, bucket, E);
    k_gather<<<4096, 256, 0, stream>>>(offs, bucket, xw, deg, b1, h, N);
    k_mlp<<<512, 256, 0, stream>>>(h, Wm1, bm1, Wm2, bm2, sbuf, N);
    k_rowred<<<128, 256, 0, stream>>>(sbuf, cnt, ssg, cag, csg, N);
    k_trace2<<<4096, 256, 0, stream>>>(offs, bucket, sbuf, trg, N);
    k_final<<<1, 256, 0, stream>>>(ssg, cag, csg, trg, (float)E, (float)N, out + (size_t)N * 64);
}

// Round 4
// 354.797 us; speedup vs baseline: 1.6400x; 1.4483x over previous
//
#include <hip/hip_runtime.h>
#include <hip/hip_bf16.h>

// ---- degrees: deg[c] += w_e (gcn) ; cnt[c] += 1 (dmon + bucket sizes) -------
__global__ void k_deg(const int* __restrict__ ei, const float* __restrict__ ew,
                      float* __restrict__ deg, int* __restrict__ cnt, int E) {
    int e = blockIdx.x * blockDim.x + threadIdx.x;
    if (e < E) {
        int c = ei[E + e];
        atomicAdd(deg + c, ew[e]);
        atomicAdd(cnt + c, 1);
    }
}

// ---- exclusive prefix sum of cnt -> offs[0..N]; fused dis = rsqrt(deg+1) ----
__global__ void k_scan(const int* __restrict__ cnt, int* __restrict__ offs,
                       float* __restrict__ deg, int N) {
    __shared__ int part[1024];
    int tid = threadIdx.x;
    int C = (N + 1023) / 1024;   // 16 for N=16384
    int base = tid * C;
    int loc[16];
    int sum = 0;
#pragma unroll
    for (int i = 0; i < 16; ++i) {
        if (i < C) {
            int idx = base + i;
            loc[i] = sum;
            sum += (idx < N) ? cnt[idx] : 0;
        }
    }
    part[tid] = sum;
    __syncthreads();
    for (int o = 1; o < 1024; o <<= 1) {
        int t = (tid >= o) ? part[tid - o] : 0;
        __syncthreads();
        part[tid] += t;
        __syncthreads();
    }
    int excl = part[tid] - sum;
#pragma unroll
    for (int i = 0; i < 16; ++i) {
        if (i < C) {
            int idx = base + i;
            if (idx < N) offs[idx] = excl + loc[i];
        }
    }
    if (tid == 1023) offs[N] = part[tid];
    for (int i = tid; i < N; i += 1024) deg[i] = rsqrtf(deg[i] + 1.0f);
}

// ---- xw = x @ W1  [N,128]x[128,64]: 16-row LDS tile, 4 rows/wave, no shfl ---
__global__ __launch_bounds__(256) void k_xw(const float* __restrict__ x,
                                            const float* __restrict__ W1,
                                            float* __restrict__ xw, int N) {
    __shared__ float  w1l[128 * 64];   // 32 KB
    __shared__ float4 xt[16][32];      // 8 KB: 16 rows x 128 floats
    for (int t = threadIdx.x; t < 128 * 64; t += 256) w1l[t] = W1[t];
    int lane = threadIdx.x & 63;
    int wv   = threadIdx.x >> 6;
    for (int base = blockIdx.x * 16; base < N; base += gridDim.x * 16) {
        __syncthreads();   // also covers w1l staging on first pass
        for (int t = threadIdx.x; t < 16 * 32; t += 256)
            ((float4*)xt)[t] = ((const float4*)x)[(size_t)base * 32 + t];
        __syncthreads();
        int r0 = wv * 4;
        float a0 = 0.f, a1 = 0.f, a2 = 0.f, a3 = 0.f;
#pragma unroll
        for (int q = 0; q < 32; ++q) {
            float4 x0 = xt[r0][q], x1 = xt[r0 + 1][q], x2 = xt[r0 + 2][q], x3 = xt[r0 + 3][q];
            float wa = w1l[(4 * q + 0) * 64 + lane];
            float wb = w1l[(4 * q + 1) * 64 + lane];
            float wc = w1l[(4 * q + 2) * 64 + lane];
            float wd = w1l[(4 * q + 3) * 64 + lane];
            a0 = fmaf(x0.x, wa, a0); a0 = fmaf(x0.y, wb, a0); a0 = fmaf(x0.z, wc, a0); a0 = fmaf(x0.w, wd, a0);
            a1 = fmaf(x1.x, wa, a1); a1 = fmaf(x1.y, wb, a1); a1 = fmaf(x1.z, wc, a1); a1 = fmaf(x1.w, wd, a1);
            a2 = fmaf(x2.x, wa, a2); a2 = fmaf(x2.y, wb, a2); a2 = fmaf(x2.z, wc, a2); a2 = fmaf(x2.w, wd, a2);
            a3 = fmaf(x3.x, wa, a3); a3 = fmaf(x3.y, wb, a3); a3 = fmaf(x3.z, wc, a3); a3 = fmaf(x3.w, wd, a3);
        }
        int gr = base + r0;
        xw[(size_t)(gr + 0) * 64 + lane] = a0;
        xw[(size_t)(gr + 1) * 64 + lane] = a1;
        xw[(size_t)(gr + 2) * 64 + lane] = a2;
        xw[(size_t)(gr + 3) * 64 + lane] = a3;
    }
}

// ---- counting-sort edges into per-target buckets: (r, norm) -----------------
__global__ void k_bucket(const int* __restrict__ ei, const float* __restrict__ ew,
                         const float* __restrict__ dis, const int* __restrict__ offs,
                         int* __restrict__ cursor, int2* __restrict__ bucket, int E) {
    int e = blockIdx.x * blockDim.x + threadIdx.x;
    if (e < E) {
        int r = ei[e], c = ei[E + e];
        float norm = dis[r] * ew[e] * dis[c];
        int pos = offs[c] + atomicAdd(&cursor[c], 1);
        bucket[pos] = make_int2(r, __float_as_int(norm));
    }
}

// ---- per-row gather: h[c,:] = relu(sum_e xw[r_e,:]*norm_e + self + b1) ------
__global__ void k_gather(const int* __restrict__ offs, const int2* __restrict__ bucket,
                         const float* __restrict__ xw, const float* __restrict__ dis,
                         const float* __restrict__ b1, float* __restrict__ h, int N) {
    int lane = threadIdx.x & 63;
    int wid  = blockIdx.x * (blockDim.x >> 6) + (threadIdx.x >> 6);
    int nw   = (blockDim.x >> 6) * gridDim.x;
    for (int c = wid; c < N; c += nw) {
        int beg = offs[c], end = offs[c + 1];
        float d = dis[c];
        float a0 = xw[(size_t)c * 64 + lane] * d * d, a1 = 0.f, a2 = 0.f, a3 = 0.f;
        for (int i = beg; i < end; i += 64) {
            int nloc = min(64, end - i);
            int2 b = (i + lane < end) ? bucket[i + lane] : make_int2(0, 0);
            int rv = b.x;
            float nv = __int_as_float(b.y);
            int j = 0;
            for (; j + 4 <= nloc; j += 4) {
                int   r0 = __shfl(rv, j),     r1 = __shfl(rv, j + 1);
                int   r2 = __shfl(rv, j + 2), r3 = __shfl(rv, j + 3);
                float n0 = __shfl(nv, j),     n1 = __shfl(nv, j + 1);
                float n2 = __shfl(nv, j + 2), n3 = __shfl(nv, j + 3);
                a0 = fmaf(xw[(size_t)r0 * 64 + lane], n0, a0);
                a1 = fmaf(xw[(size_t)r1 * 64 + lane], n1, a1);
                a2 = fmaf(xw[(size_t)r2 * 64 + lane], n2, a2);
                a3 = fmaf(xw[(size_t)r3 * 64 + lane], n3, a3);
            }
            for (; j < nloc; ++j) {
                int r = __shfl(rv, j);
                float nm = __shfl(nv, j);
                a0 = fmaf(xw[(size_t)r * 64 + lane], nm, a0);
            }
        }
        float v = a0 + a1 + a2 + a3 + b1[lane];
        h[(size_t)c * 64 + lane] = v > 0.f ? v : 0.f;
    }
}

// ---- s = softmax((h@Wm1+bm1)@Wm2+bm2): 16-row tile, 4 rows/wave -------------
__global__ __launch_bounds__(256) void k_mlp(const float* __restrict__ h,
                      const float* __restrict__ Wm1, const float* __restrict__ bm1,
                      const float* __restrict__ Wm2, const float* __restrict__ bm2,
                      float* __restrict__ s, int N) {
    __shared__ float  w1l[4096], w2l[4096], b1l[64], b2l[64];
    __shared__ float4 ht[16][16];      // 4 KB
    __shared__ float  tt[4][4][64];    // 4 KB per-wave layer-1 scratch
    for (int t = threadIdx.x; t < 4096; t += 256) {
        w1l[t] = Wm1[t];
        w2l[t] = Wm2[t];
    }
    if (threadIdx.x < 64) {
        b1l[threadIdx.x] = bm1[threadIdx.x];
        b2l[threadIdx.x] = bm2[threadIdx.x];
    }
    int lane = threadIdx.x & 63;
    int wv   = threadIdx.x >> 6;
    for (int base = blockIdx.x * 16; base < N; base += gridDim.x * 16) {
        __syncthreads();
        for (int t = threadIdx.x; t < 16 * 16; t += 256)
            ((float4*)ht)[t] = ((const float4*)h)[(size_t)base * 16 + t];
        __syncthreads();
        int r0 = wv * 4;
        float t0 = b1l[lane], t1 = t0, t2 = t0, t3 = t0;
#pragma unroll
        for (int q = 0; q < 16; ++q) {
            float4 h0 = ht[r0][q], h1 = ht[r0 + 1][q], h2 = ht[r0 + 2][q], h3 = ht[r0 + 3][q];
            float wa = w1l[(4 * q + 0) * 64 + lane];
            float wb = w1l[(4 * q + 1) * 64 + lane];
            float wc = w1l[(4 * q + 2) * 64 + lane];
            float wd = w1l[(4 * q + 3) * 64 + lane];
            t0 = fmaf(h0.x, wa, t0); t0 = fmaf(h0.y, wb, t0); t0 = fmaf(h0.z, wc, t0); t0 = fmaf(h0.w, wd, t0);
            t1 = fmaf(h1.x, wa, t1); t1 = fmaf(h1.y, wb, t1); t1 = fmaf(h1.z, wc, t1); t1 = fmaf(h1.w, wd, t1);
            t2 = fmaf(h2.x, wa, t2); t2 = fmaf(h2.y, wb, t2); t2 = fmaf(h2.z, wc, t2); t2 = fmaf(h2.w, wd, t2);
            t3 = fmaf(h3.x, wa, t3); t3 = fmaf(h3.y, wb, t3); t3 = fmaf(h3.z, wc, t3); t3 = fmaf(h3.w, wd, t3);
        }
        tt[wv][0][lane] = t0; tt[wv][1][lane] = t1;
        tt[wv][2][lane] = t2; tt[wv][3][lane] = t3;
        __syncthreads();
        float g0 = b2l[lane], g1 = g0, g2 = g0, g3 = g0;
#pragma unroll
        for (int q = 0; q < 16; ++q) {
            float4 u0 = ((float4*)tt[wv][0])[q], u1 = ((float4*)tt[wv][1])[q];
            float4 u2 = ((float4*)tt[wv][2])[q], u3 = ((float4*)tt[wv][3])[q];
            float wa = w2l[(4 * q + 0) * 64 + lane];
            float wb = w2l[(4 * q + 1) * 64 + lane];
            float wc = w2l[(4 * q + 2) * 64 + lane];
            float wd = w2l[(4 * q + 3) * 64 + lane];
            g0 = fmaf(u0.x, wa, g0); g0 = fmaf(u0.y, wb, g0); g0 = fmaf(u0.z, wc, g0); g0 = fmaf(u0.w, wd, g0);
            g1 = fmaf(u1.x, wa, g1); g1 = fmaf(u1.y, wb, g1); g1 = fmaf(u1.z, wc, g1); g1 = fmaf(u1.w, wd, g1);
            g2 = fmaf(u2.x, wa, g2); g2 = fmaf(u2.y, wb, g2); g2 = fmaf(u2.z, wc, g2); g2 = fmaf(u2.w, wd, g2);
            g3 = fmaf(u3.x, wa, g3); g3 = fmaf(u3.y, wb, g3); g3 = fmaf(u3.z, wc, g3); g3 = fmaf(u3.w, wd, g3);
        }
        float m0 = g0, m1 = g1, m2 = g2, m3 = g3;
#pragma unroll
        for (int o = 32; o > 0; o >>= 1) {
            m0 = fmaxf(m0, __shfl_xor(m0, o));
            m1 = fmaxf(m1, __shfl_xor(m1, o));
            m2 = fmaxf(m2, __shfl_xor(m2, o));
            m3 = fmaxf(m3, __shfl_xor(m3, o));
        }
        float e0 = __expf(g0 - m0), e1 = __expf(g1 - m1);
        float e2 = __expf(g2 - m2), e3 = __expf(g3 - m3);
        float s0 = e0, s1 = e1, s2 = e2, s3 = e3;
#pragma unroll
        for (int o = 32; o > 0; o >>= 1) {
            s0 += __shfl_xor(s0, o);
            s1 += __shfl_xor(s1, o);
            s2 += __shfl_xor(s2, o);
            s3 += __shfl_xor(s3, o);
        }
        int gr = base + r0;
        s[(size_t)(gr + 0) * 64 + lane] = e0 / s0;
        s[(size_t)(gr + 1) * 64 + lane] = e1 / s1;
        s[(size_t)(gr + 2) * 64 + lane] = e2 / s2;
        s[(size_t)(gr + 3) * 64 + lane] = e3 / s3;
    }
}

// ---- row reductions: ss = s^T s, cs = colsum(s), ca = s^T deg ---------------
__global__ void k_rowred(const float* __restrict__ s, const int* __restrict__ cnt,
                         float* __restrict__ ssg, float* __restrict__ cag,
                         float* __restrict__ csg, int N) {
    __shared__ float ssl[4096];
    for (int t = threadIdx.x; t < 4096; t += blockDim.x) ssl[t] = 0.f;
    __syncthreads();
    int lane = threadIdx.x & 63;
    int wid  = threadIdx.x >> 6;
    int nw   = (blockDim.x >> 6) * gridDim.x;
    float ssacc[64];
#pragma unroll
    for (int a = 0; a < 64; ++a) ssacc[a] = 0.f;
    float csj = 0.f, caj = 0.f;
    for (int row = blockIdx.x * (blockDim.x >> 6) + wid; row < N; row += nw) {
        float sj = s[(size_t)row * 64 + lane];
        float d = (float)cnt[row];
        csj += sj;
        caj += sj * d;
#pragma unroll
        for (int a = 0; a < 64; ++a) ssacc[a] = fmaf(__shfl(sj, a), sj, ssacc[a]);
    }
#pragma unroll
    for (int a = 0; a < 64; ++a) atomicAdd(&ssl[a * 64 + lane], ssacc[a]);
    atomicAdd(&csg[lane], csj);
    atomicAdd(&cag[lane], caj);
    __syncthreads();
    for (int t = threadIdx.x; t < 4096; t += blockDim.x) atomicAdd(&ssg[t], ssl[t]);
}

// ---- trace via buckets: per row c, vsum = sum_e s[r_e,:]; tr += dot(vsum,s[c])
__global__ void k_trace2(const int* __restrict__ offs, const int2* __restrict__ bucket,
                         const float* __restrict__ s, float* __restrict__ traceg, int N) {
    int lane = threadIdx.x & 63;
    int wid  = blockIdx.x * (blockDim.x >> 6) + (threadIdx.x >> 6);
    int nw   = (blockDim.x >> 6) * gridDim.x;
    float acc = 0.f;
    for (int c = wid; c < N; c += nw) {
        int beg = offs[c], end = offs[c + 1];
        float v0 = 0.f, v1 = 0.f, v2 = 0.f, v3 = 0.f;
        for (int i = beg; i < end; i += 64) {
            int nloc = min(64, end - i);
            int rvv = (i + lane < end) ? bucket[i + lane].x : 0;
            int j = 0;
            for (; j + 4 <= nloc; j += 4) {
                int r0 = __shfl(rvv, j),     r1 = __shfl(rvv, j + 1);
                int r2 = __shfl(rvv, j + 2), r3 = __shfl(rvv, j + 3);
                v0 += s[(size_t)r0 * 64 + lane];
                v1 += s[(size_t)r1 * 64 + lane];
                v2 += s[(size_t)r2 * 64 + lane];
                v3 += s[(size_t)r3 * 64 + lane];
            }
            for (; j < nloc; ++j) {
                int r = __shfl(rvv, j);
                v0 += s[(size_t)r * 64 + lane];
            }
        }
        acc = fmaf(v0 + v1 + v2 + v3, s[(size_t)c * 64 + lane], acc);
    }
#pragma unroll
    for (int o = 32; o > 0; o >>= 1) acc += __shfl_xor(acc, o);
    __shared__ float bsum;
    if (threadIdx.x == 0) bsum = 0.f;
    __syncthreads();
    if (lane == 0) atomicAdd(&bsum, acc);
    __syncthreads();
    if (threadIdx.x == 0) atomicAdd(traceg, bsum);
}

// ---- finalize: spectral + ortho + cluster loss ------------------------------
__global__ void k_final(const float* __restrict__ ssg, const float* __restrict__ cag,
                        const float* __restrict__ csg, const float* __restrict__ traceg,
                        float Ef, float Nf, float* __restrict__ out) {
    __shared__ float red[256];
    int tid = threadIdx.x;

    float a = 0.f;
    for (int t = tid; t < 4096; t += 256) { float v = ssg[t]; a += v * v; }
    red[tid] = a; __syncthreads();
    for (int o = 128; o > 0; o >>= 1) { if (tid < o) red[tid] += red[tid + o]; __syncthreads(); }
    float ss_sumsq = red[0]; __syncthreads();

    a = (tid < 64) ? ssg[tid * 64 + tid] : 0.f;
    red[tid] = a; __syncthreads();
    for (int o = 128; o > 0; o >>= 1) { if (tid < o) red[tid] += red[tid + o]; __syncthreads(); }
    float tr_ss = red[0]; __syncthreads();

    a = (tid < 64) ? cag[tid] * cag[tid] : 0.f;
    red[tid] = a; __syncthreads();
    for (int o = 128; o > 0; o >>= 1) { if (tid < o) red[tid] += red[tid + o]; __syncthreads(); }
    float ca_ss = red[0]; __syncthreads();

    a = (tid < 64) ? csg[tid] * csg[tid] : 0.f;
    red[tid] = a; __syncthreads();
    for (int o = 128; o > 0; o >>= 1) { if (tid < o) red[tid] += red[tid + o]; __syncthreads(); }
    float cs_ss = red[0];

    if (tid == 0) {
        // 2m = deg.sum() = E
        float spec = -(traceg[0] - ca_ss / Ef) / Ef;
        float ss_fro = sqrtf(ss_sumsq);
        // ||ss/fro - I/8||_F^2 = 1 - tr(ss)/(4*fro) + 1
        float ortho = sqrtf(fmaxf(2.f - tr_ss / (4.f * ss_fro), 0.f));
        float clus = sqrtf(cs_ss) / Nf * 8.f - 1.f;
        out[0] = spec + ortho + clus;
    }
}

extern "C" void kernel_launch(void* const* d_in, const int* in_sizes, int n_in,
                              void* d_out, int out_size, void* d_ws, size_t ws_size,
                              hipStream_t stream) {
    const float* x   = (const float*)d_in[0];
    const int*   ei  = (const int*)d_in[1];
    const float* ew  = (const float*)d_in[2];
    const float* W1  = (const float*)d_in[3];
    const float* b1  = (const float*)d_in[4];
    const float* Wm1 = (const float*)d_in[5];
    const float* bm1 = (const float*)d_in[6];
    const float* Wm2 = (const float*)d_in[7];
    const float* bm2 = (const float*)d_in[8];
    float* out = (float*)d_out;

    const int N = in_sizes[0] / 128;   // 16384
    const int E = in_sizes[2];         // 524288

    float* ws = (float*)d_ws;
    // --- zeroed region ---
    float* deg    = ws;                       // N  (-> dis in place after k_scan)
    int*   cnt    = (int*)(ws + N);           // N
    int*   cursor = cnt + N;                  // N
    float* ssg    = (float*)(cursor + N);     // 4096
    float* cag    = ssg + 4096;               // 64
    float* csg    = cag + 64;                 // 64
    float* trg    = csg + 64;                 // 1
    // --- uninitialized region ---
    float* xw = trg + 1;                      // N*64
    float* h  = xw + (size_t)N * 64;          // N*64
    size_t foff = (size_t)(h + (size_t)N * 64 - ws);
    foff = (foff + 1) & ~(size_t)1;           // 8B-align for int2
    int2* bucket = (int2*)(ws + foff);        // E int2
    int*  offs   = (int*)(bucket + E);        // N+1
    float* sbuf  = out;                       // s lives in d_out (f32 output 0)

    size_t zbytes = ((size_t)3 * N + 4096 + 64 + 64 + 1) * sizeof(float);
    hipMemsetAsync(d_ws, 0, zbytes, stream);

    k_deg<<<(E + 255) / 256, 256, 0, stream>>>(ei, ew, deg, cnt, E);
    k_scan<<<1, 1024, 0, stream>>>(cnt, offs, deg, N);
    k_xw<<<512, 256, 0, stream>>>(x, W1, xw, N);
    k_bucket<<<(E + 255) / 256, 256, 0, stream>>>(ei, ew, deg, offs, cursor, bucket, E);
    k_gather<<<4096, 256, 0, stream>>>(offs, bucket, xw, deg, b1, h, N);
    k_mlp<<<512, 256, 0, stream>>>(h, Wm1, bm1, Wm2, bm2, sbuf, N);
    k_rowred<<<128, 256, 0, stream>>>(sbuf, cnt, ssg, cag, csg, N);
    k_trace2<<<4096, 256, 0, stream>>>(offs, bucket, sbuf, trg, N);
    k_final<<<1, 256, 0, stream>>>(ssg, cag, csg, trg, (float)E, (float)N, out + (size_t)N * 64);
}

// Round 5
// 314.368 us; speedup vs baseline: 1.8509x; 1.1286x over previous
//
#include <hip/hip_runtime.h>
#include <hip/hip_bf16.h>

// ---- degrees: deg[c] += w_e (gcn) ; cnt[c] += 1 (dmon + bucket sizes) -------
__global__ void k_deg(const int* __restrict__ ei, const float* __restrict__ ew,
                      float* __restrict__ deg, int* __restrict__ cnt, int E) {
    int e = blockIdx.x * blockDim.x + threadIdx.x;
    if (e < E) {
        int c = ei[E + e];
        atomicAdd(deg + c, ew[e]);
        atomicAdd(cnt + c, 1);
    }
}

// ---- exclusive prefix sum of cnt -> offs[0..N]; fused dis = rsqrt(deg+1) ----
__global__ void k_scan(const int* __restrict__ cnt, int* __restrict__ offs,
                       float* __restrict__ deg, int N) {
    __shared__ int part[1024];
    int tid = threadIdx.x;
    int C = (N + 1023) / 1024;   // 16 for N=16384
    int base = tid * C;
    int loc[16];
    int sum = 0;
#pragma unroll
    for (int i = 0; i < 16; ++i) {
        if (i < C) {
            int idx = base + i;
            loc[i] = sum;
            sum += (idx < N) ? cnt[idx] : 0;
        }
    }
    part[tid] = sum;
    __syncthreads();
    for (int o = 1; o < 1024; o <<= 1) {
        int t = (tid >= o) ? part[tid - o] : 0;
        __syncthreads();
        part[tid] += t;
        __syncthreads();
    }
    int excl = part[tid] - sum;
#pragma unroll
    for (int i = 0; i < 16; ++i) {
        if (i < C) {
            int idx = base + i;
            if (idx < N) offs[idx] = excl + loc[i];
        }
    }
    if (tid == 1023) offs[N] = part[tid];
    for (int i = tid; i < N; i += 1024) deg[i] = rsqrtf(deg[i] + 1.0f);
}

// ---- xw = x @ W1  [N,128]x[128,64]: 16-row LDS tile, 4 rows/wave, no shfl ---
__global__ __launch_bounds__(256) void k_xw(const float* __restrict__ x,
                                            const float* __restrict__ W1,
                                            float* __restrict__ xw, int N) {
    __shared__ float  w1l[128 * 64];   // 32 KB
    __shared__ float4 xt[16][32];      // 8 KB: 16 rows x 128 floats
    for (int t = threadIdx.x; t < 128 * 64; t += 256) w1l[t] = W1[t];
    int lane = threadIdx.x & 63;
    int wv   = threadIdx.x >> 6;
    for (int base = blockIdx.x * 16; base < N; base += gridDim.x * 16) {
        __syncthreads();   // also covers w1l staging on first pass
        for (int t = threadIdx.x; t < 16 * 32; t += 256)
            ((float4*)xt)[t] = ((const float4*)x)[(size_t)base * 32 + t];
        __syncthreads();
        int r0 = wv * 4;
        float a0 = 0.f, a1 = 0.f, a2 = 0.f, a3 = 0.f;
#pragma unroll
        for (int q = 0; q < 32; ++q) {
            float4 x0 = xt[r0][q], x1 = xt[r0 + 1][q], x2 = xt[r0 + 2][q], x3 = xt[r0 + 3][q];
            float wa = w1l[(4 * q + 0) * 64 + lane];
            float wb = w1l[(4 * q + 1) * 64 + lane];
            float wc = w1l[(4 * q + 2) * 64 + lane];
            float wd = w1l[(4 * q + 3) * 64 + lane];
            a0 = fmaf(x0.x, wa, a0); a0 = fmaf(x0.y, wb, a0); a0 = fmaf(x0.z, wc, a0); a0 = fmaf(x0.w, wd, a0);
            a1 = fmaf(x1.x, wa, a1); a1 = fmaf(x1.y, wb, a1); a1 = fmaf(x1.z, wc, a1); a1 = fmaf(x1.w, wd, a1);
            a2 = fmaf(x2.x, wa, a2); a2 = fmaf(x2.y, wb, a2); a2 = fmaf(x2.z, wc, a2); a2 = fmaf(x2.w, wd, a2);
            a3 = fmaf(x3.x, wa, a3); a3 = fmaf(x3.y, wb, a3); a3 = fmaf(x3.z, wc, a3); a3 = fmaf(x3.w, wd, a3);
        }
        int gr = base + r0;
        xw[(size_t)(gr + 0) * 64 + lane] = a0;
        xw[(size_t)(gr + 1) * 64 + lane] = a1;
        xw[(size_t)(gr + 2) * 64 + lane] = a2;
        xw[(size_t)(gr + 3) * 64 + lane] = a3;
    }
}

// ---- counting-sort edges into per-target buckets: (r, norm) -----------------
__global__ void k_bucket(const int* __restrict__ ei, const float* __restrict__ ew,
                         const float* __restrict__ dis, const int* __restrict__ offs,
                         int* __restrict__ cursor, int2* __restrict__ bucket, int E) {
    int e = blockIdx.x * blockDim.x + threadIdx.x;
    if (e < E) {
        int r = ei[e], c = ei[E + e];
        float norm = dis[r] * ew[e] * dis[c];
        int pos = offs[c] + atomicAdd(&cursor[c], 1);
        bucket[pos] = make_int2(r, __float_as_int(norm));
    }
}

// ---- per-row gather: h[c,:] = relu(sum_e xw[r_e,:]*norm_e + self + b1) ------
__global__ void k_gather(const int* __restrict__ offs, const int2* __restrict__ bucket,
                         const float* __restrict__ xw, const float* __restrict__ dis,
                         const float* __restrict__ b1, float* __restrict__ h, int N) {
    int lane = threadIdx.x & 63;
    int wid  = blockIdx.x * (blockDim.x >> 6) + (threadIdx.x >> 6);
    int nw   = (blockDim.x >> 6) * gridDim.x;
    for (int c = wid; c < N; c += nw) {
        int beg = offs[c], end = offs[c + 1];
        float d = dis[c];
        float a0 = xw[(size_t)c * 64 + lane] * d * d, a1 = 0.f, a2 = 0.f, a3 = 0.f;
        for (int i = beg; i < end; i += 64) {
            int nloc = min(64, end - i);
            int2 b = (i + lane < end) ? bucket[i + lane] : make_int2(0, 0);
            int rv = b.x;
            float nv = __int_as_float(b.y);
            int j = 0;
            for (; j + 4 <= nloc; j += 4) {
                int   r0 = __shfl(rv, j),     r1 = __shfl(rv, j + 1);
                int   r2 = __shfl(rv, j + 2), r3 = __shfl(rv, j + 3);
                float n0 = __shfl(nv, j),     n1 = __shfl(nv, j + 1);
                float n2 = __shfl(nv, j + 2), n3 = __shfl(nv, j + 3);
                a0 = fmaf(xw[(size_t)r0 * 64 + lane], n0, a0);
                a1 = fmaf(xw[(size_t)r1 * 64 + lane], n1, a1);
                a2 = fmaf(xw[(size_t)r2 * 64 + lane], n2, a2);
                a3 = fmaf(xw[(size_t)r3 * 64 + lane], n3, a3);
            }
            for (; j < nloc; ++j) {
                int r = __shfl(rv, j);
                float nm = __shfl(nv, j);
                a0 = fmaf(xw[(size_t)r * 64 + lane], nm, a0);
            }
        }
        float v = a0 + a1 + a2 + a3 + b1[lane];
        h[(size_t)c * 64 + lane] = v > 0.f ? v : 0.f;
    }
}

// ---- s = softmax((h@Wm1+bm1)@Wm2+bm2): 16-row tile, 4 rows/wave -------------
__global__ __launch_bounds__(256) void k_mlp(const float* __restrict__ h,
                      const float* __restrict__ Wm1, const float* __restrict__ bm1,
                      const float* __restrict__ Wm2, const float* __restrict__ bm2,
                      float* __restrict__ s, int N) {
    __shared__ float  w1l[4096], w2l[4096], b1l[64], b2l[64];
    __shared__ float4 ht[16][16];      // 4 KB
    __shared__ float  tt[4][4][64];    // 4 KB per-wave layer-1 scratch
    for (int t = threadIdx.x; t < 4096; t += 256) {
        w1l[t] = Wm1[t];
        w2l[t] = Wm2[t];
    }
    if (threadIdx.x < 64) {
        b1l[threadIdx.x] = bm1[threadIdx.x];
        b2l[threadIdx.x] = bm2[threadIdx.x];
    }
    int lane = threadIdx.x & 63;
    int wv   = threadIdx.x >> 6;
    for (int base = blockIdx.x * 16; base < N; base += gridDim.x * 16) {
        __syncthreads();
        for (int t = threadIdx.x; t < 16 * 16; t += 256)
            ((float4*)ht)[t] = ((const float4*)h)[(size_t)base * 16 + t];
        __syncthreads();
        int r0 = wv * 4;
        float t0 = b1l[lane], t1 = t0, t2 = t0, t3 = t0;
#pragma unroll
        for (int q = 0; q < 16; ++q) {
            float4 h0 = ht[r0][q], h1 = ht[r0 + 1][q], h2 = ht[r0 + 2][q], h3 = ht[r0 + 3][q];
            float wa = w1l[(4 * q + 0) * 64 + lane];
            float wb = w1l[(4 * q + 1) * 64 + lane];
            float wc = w1l[(4 * q + 2) * 64 + lane];
            float wd = w1l[(4 * q + 3) * 64 + lane];
            t0 = fmaf(h0.x, wa, t0); t0 = fmaf(h0.y, wb, t0); t0 = fmaf(h0.z, wc, t0); t0 = fmaf(h0.w, wd, t0);
            t1 = fmaf(h1.x, wa, t1); t1 = fmaf(h1.y, wb, t1); t1 = fmaf(h1.z, wc, t1); t1 = fmaf(h1.w, wd, t1);
            t2 = fmaf(h2.x, wa, t2); t2 = fmaf(h2.y, wb, t2); t2 = fmaf(h2.z, wc, t2); t2 = fmaf(h2.w, wd, t2);
            t3 = fmaf(h3.x, wa, t3); t3 = fmaf(h3.y, wb, t3); t3 = fmaf(h3.z, wc, t3); t3 = fmaf(h3.w, wd, t3);
        }
        tt[wv][0][lane] = t0; tt[wv][1][lane] = t1;
        tt[wv][2][lane] = t2; tt[wv][3][lane] = t3;
        __syncthreads();
        float g0 = b2l[lane], g1 = g0, g2 = g0, g3 = g0;
#pragma unroll
        for (int q = 0; q < 16; ++q) {
            float4 u0 = ((float4*)tt[wv][0])[q], u1 = ((float4*)tt[wv][1])[q];
            float4 u2 = ((float4*)tt[wv][2])[q], u3 = ((float4*)tt[wv][3])[q];
            float wa = w2l[(4 * q + 0) * 64 + lane];
            float wb = w2l[(4 * q + 1) * 64 + lane];
            float wc = w2l[(4 * q + 2) * 64 + lane];
            float wd = w2l[(4 * q + 3) * 64 + lane];
            g0 = fmaf(u0.x, wa, g0); g0 = fmaf(u0.y, wb, g0); g0 = fmaf(u0.z, wc, g0); g0 = fmaf(u0.w, wd, g0);
            g1 = fmaf(u1.x, wa, g1); g1 = fmaf(u1.y, wb, g1); g1 = fmaf(u1.z, wc, g1); g1 = fmaf(u1.w, wd, g1);
            g2 = fmaf(u2.x, wa, g2); g2 = fmaf(u2.y, wb, g2); g2 = fmaf(u2.z, wc, g2); g2 = fmaf(u2.w, wd, g2);
            g3 = fmaf(u3.x, wa, g3); g3 = fmaf(u3.y, wb, g3); g3 = fmaf(u3.z, wc, g3); g3 = fmaf(u3.w, wd, g3);
        }
        float m0 = g0, m1 = g1, m2 = g2, m3 = g3;
#pragma unroll
        for (int o = 32; o > 0; o >>= 1) {
            m0 = fmaxf(m0, __shfl_xor(m0, o));
            m1 = fmaxf(m1, __shfl_xor(m1, o));
            m2 = fmaxf(m2, __shfl_xor(m2, o));
            m3 = fmaxf(m3, __shfl_xor(m3, o));
        }
        float e0 = __expf(g0 - m0), e1 = __expf(g1 - m1);
        float e2 = __expf(g2 - m2), e3 = __expf(g3 - m3);
        float s0 = e0, s1 = e1, s2 = e2, s3 = e3;
#pragma unroll
        for (int o = 32; o > 0; o >>= 1) {
            s0 += __shfl_xor(s0, o);
            s1 += __shfl_xor(s1, o);
            s2 += __shfl_xor(s2, o);
            s3 += __shfl_xor(s3, o);
        }
        int gr = base + r0;
        s[(size_t)(gr + 0) * 64 + lane] = e0 / s0;
        s[(size_t)(gr + 1) * 64 + lane] = e1 / s1;
        s[(size_t)(gr + 2) * 64 + lane] = e2 / s2;
        s[(size_t)(gr + 3) * 64 + lane] = e3 / s3;
    }
}

// ---- row reductions via 64-row LDS tile: ss=s^T s, cs=colsum(s), ca=s^T deg -
// One tile per block; wave wv owns ss rows [wv*16, wv*16+16). Broadcast LDS
// reads (same address across wave) are free; 16 independent reads+fmas give
// the ILP the old shfl-chain version lacked.
__global__ __launch_bounds__(256) void k_rowred(const float* __restrict__ s,
                         const int* __restrict__ cnt,
                         float* __restrict__ ssg, float* __restrict__ cag,
                         float* __restrict__ csg, int N) {
    __shared__ float tile[64][64];   // 16 KB
    int lane = threadIdx.x & 63;
    int wv   = threadIdx.x >> 6;
    int base = blockIdx.x * 64;
    if (base >= N) return;
    for (int t = threadIdx.x; t < 1024; t += 256)
        ((float4*)tile)[t] = ((const float4*)(s + (size_t)base * 64))[t];
    __syncthreads();
    float acc[16];
#pragma unroll
    for (int i = 0; i < 16; ++i) acc[i] = 0.f;
    for (int r = 0; r < 64; ++r) {
        float sj = tile[r][lane];
        const float* brow = &tile[r][wv * 16];
#pragma unroll
        for (int i = 0; i < 16; ++i) acc[i] = fmaf(brow[i], sj, acc[i]);
    }
    // cs/ca partials: wave wv covers tile rows [wv*16, wv*16+16)
    float csj = 0.f, caj = 0.f;
#pragma unroll
    for (int i = 0; i < 16; ++i) {
        int r = wv * 16 + i;
        float sj = tile[r][lane];
        csj += sj;
        caj = fmaf(sj, (float)cnt[base + r], caj);
    }
#pragma unroll
    for (int i = 0; i < 16; ++i) atomicAdd(&ssg[(wv * 16 + i) * 64 + lane], acc[i]);
    atomicAdd(&csg[lane], csj);
    atomicAdd(&cag[lane], caj);
}

// ---- trace via buckets: per row c, vsum = sum_e s[r_e,:]; tr += dot(vsum,s[c])
__global__ void k_trace2(const int* __restrict__ offs, const int2* __restrict__ bucket,
                         const float* __restrict__ s, float* __restrict__ traceg, int N) {
    int lane = threadIdx.x & 63;
    int wid  = blockIdx.x * (blockDim.x >> 6) + (threadIdx.x >> 6);
    int nw   = (blockDim.x >> 6) * gridDim.x;
    float acc = 0.f;
    for (int c = wid; c < N; c += nw) {
        int beg = offs[c], end = offs[c + 1];
        float v0 = 0.f, v1 = 0.f, v2 = 0.f, v3 = 0.f;
        for (int i = beg; i < end; i += 64) {
            int nloc = min(64, end - i);
            int rvv = (i + lane < end) ? bucket[i + lane].x : 0;
            int j = 0;
            for (; j + 4 <= nloc; j += 4) {
                int r0 = __shfl(rvv, j),     r1 = __shfl(rvv, j + 1);
                int r2 = __shfl(rvv, j + 2), r3 = __shfl(rvv, j + 3);
                v0 += s[(size_t)r0 * 64 + lane];
                v1 += s[(size_t)r1 * 64 + lane];
                v2 += s[(size_t)r2 * 64 + lane];
                v3 += s[(size_t)r3 * 64 + lane];
            }
            for (; j < nloc; ++j) {
                int r = __shfl(rvv, j);
                v0 += s[(size_t)r * 64 + lane];
            }
        }
        acc = fmaf(v0 + v1 + v2 + v3, s[(size_t)c * 64 + lane], acc);
    }
#pragma unroll
    for (int o = 32; o > 0; o >>= 1) acc += __shfl_xor(acc, o);
    __shared__ float bsum;
    if (threadIdx.x == 0) bsum = 0.f;
    __syncthreads();
    if (lane == 0) atomicAdd(&bsum, acc);
    __syncthreads();
    if (threadIdx.x == 0) atomicAdd(traceg, bsum);
}

// ---- finalize: spectral + ortho + cluster loss ------------------------------
__global__ void k_final(const float* __restrict__ ssg, const float* __restrict__ cag,
                        const float* __restrict__ csg, const float* __restrict__ traceg,
                        float Ef, float Nf, float* __restrict__ out) {
    __shared__ float red[256];
    int tid = threadIdx.x;

    float a = 0.f;
    for (int t = tid; t < 4096; t += 256) { float v = ssg[t]; a += v * v; }
    red[tid] = a; __syncthreads();
    for (int o = 128; o > 0; o >>= 1) { if (tid < o) red[tid] += red[tid + o]; __syncthreads(); }
    float ss_sumsq = red[0]; __syncthreads();

    a = (tid < 64) ? ssg[tid * 64 + tid] : 0.f;
    red[tid] = a; __syncthreads();
    for (int o = 128; o > 0; o >>= 1) { if (tid < o) red[tid] += red[tid + o]; __syncthreads(); }
    float tr_ss = red[0]; __syncthreads();

    a = (tid < 64) ? cag[tid] * cag[tid] : 0.f;
    red[tid] = a; __syncthreads();
    for (int o = 128; o > 0; o >>= 1) { if (tid < o) red[tid] += red[tid + o]; __syncthreads(); }
    float ca_ss = red[0]; __syncthreads();

    a = (tid < 64) ? csg[tid] * csg[tid] : 0.f;
    red[tid] = a; __syncthreads();
    for (int o = 128; o > 0; o >>= 1) { if (tid < o) red[tid] += red[tid + o]; __syncthreads(); }
    float cs_ss = red[0];

    if (tid == 0) {
        // 2m = deg.sum() = E
        float spec = -(traceg[0] - ca_ss / Ef) / Ef;
        float ss_fro = sqrtf(ss_sumsq);
        // ||ss/fro - I/8||_F^2 = 1 - tr(ss)/(4*fro) + 1
        float ortho = sqrtf(fmaxf(2.f - tr_ss / (4.f * ss_fro), 0.f));
        float clus = sqrtf(cs_ss) / Nf * 8.f - 1.f;
        out[0] = spec + ortho + clus;
    }
}

extern "C" void kernel_launch(void* const* d_in, const int* in_sizes, int n_in,
                              void* d_out, int out_size, void* d_ws, size_t ws_size,
                              hipStream_t stream) {
    const float* x   = (const float*)d_in[0];
    const int*   ei  = (const int*)d_in[1];
    const float* ew  = (const float*)d_in[2];
    const float* W1  = (const float*)d_in[3];
    const float* b1  = (const float*)d_in[4];
    const float* Wm1 = (const float*)d_in[5];
    const float* bm1 = (const float*)d_in[6];
    const float* Wm2 = (const float*)d_in[7];
    const float* bm2 = (const float*)d_in[8];
    float* out = (float*)d_out;

    const int N = in_sizes[0] / 128;   // 16384
    const int E = in_sizes[2];         // 524288

    float* ws = (float*)d_ws;
    // --- zeroed region ---
    float* deg    = ws;                       // N  (-> dis in place after k_scan)
    int*   cnt    = (int*)(ws + N);           // N
    int*   cursor = cnt + N;                  // N
    float* ssg    = (float*)(cursor + N);     // 4096
    float* cag    = ssg + 4096;               // 64
    float* csg    = cag + 64;                 // 64
    float* trg    = csg + 64;                 // 1
    // --- uninitialized region ---
    float* xw = trg + 1;                      // N*64
    float* h  = xw + (size_t)N * 64;          // N*64
    size_t foff = (size_t)(h + (size_t)N * 64 - ws);
    foff = (foff + 1) & ~(size_t)1;           // 8B-align for int2
    int2* bucket = (int2*)(ws + foff);        // E int2
    int*  offs   = (int*)(bucket + E);        // N+1
    float* sbuf  = out;                       // s lives in d_out (f32 output 0)

    size_t zbytes = ((size_t)3 * N + 4096 + 64 + 64 + 1) * sizeof(float);
    hipMemsetAsync(d_ws, 0, zbytes, stream);

    k_deg<<<(E + 255) / 256, 256, 0, stream>>>(ei, ew, deg, cnt, E);
    k_scan<<<1, 1024, 0, stream>>>(cnt, offs, deg, N);
    k_xw<<<512, 256, 0, stream>>>(x, W1, xw, N);
    k_bucket<<<(E + 255) / 256, 256, 0, stream>>>(ei, ew, deg, offs, cursor, bucket, E);
    k_gather<<<4096, 256, 0, stream>>>(offs, bucket, xw, deg, b1, h, N);
    k_mlp<<<512, 256, 0, stream>>>(h, Wm1, bm1, Wm2, bm2, sbuf, N);
    k_rowred<<<(N + 63) / 64, 256, 0, stream>>>(sbuf, cnt, ssg, cag, csg, N);
    k_trace2<<<4096, 256, 0, stream>>>(offs, bucket, sbuf, trg, N);
    k_final<<<1, 256, 0, stream>>>(ssg, cag, csg, trg, (float)E, (float)N, out + (size_t)N * 64);
}

// Round 6
// 312.452 us; speedup vs baseline: 1.8622x; 1.0061x over previous
//
#include <hip/hip_runtime.h>
#include <hip/hip_bf16.h>

// ---- degrees: deg[c] += w_e (gcn) ; cnt[c] += 1 (dmon + bucket sizes) -------
__global__ void k_deg(const int* __restrict__ ei, const float* __restrict__ ew,
                      float* __restrict__ deg, int* __restrict__ cnt, int E) {
    int e = blockIdx.x * blockDim.x + threadIdx.x;
    if (e < E) {
        int c = ei[E + e];
        atomicAdd(deg + c, ew[e]);
        atomicAdd(cnt + c, 1);
    }
}

// ---- exclusive prefix sum of cnt -> offs[0..N]; fused dis = rsqrt(deg+1) ----
__global__ void k_scan(const int* __restrict__ cnt, int* __restrict__ offs,
                       float* __restrict__ deg, int N) {
    __shared__ int part[1024];
    int tid = threadIdx.x;
    int C = (N + 1023) / 1024;   // 16 for N=16384
    int base = tid * C;
    int loc[16];
    int sum = 0;
#pragma unroll
    for (int i = 0; i < 16; ++i) {
        if (i < C) {
            int idx = base + i;
            loc[i] = sum;
            sum += (idx < N) ? cnt[idx] : 0;
        }
    }
    part[tid] = sum;
    __syncthreads();
    for (int o = 1; o < 1024; o <<= 1) {
        int t = (tid >= o) ? part[tid - o] : 0;
        __syncthreads();
        part[tid] += t;
        __syncthreads();
    }
    int excl = part[tid] - sum;
#pragma unroll
    for (int i = 0; i < 16; ++i) {
        if (i < C) {
            int idx = base + i;
            if (idx < N) offs[idx] = excl + loc[i];
        }
    }
    if (tid == 1023) offs[N] = part[tid];
    for (int i = tid; i < N; i += 1024) deg[i] = rsqrtf(deg[i] + 1.0f);
}

// ---- xw = x @ W1  [N,128]x[128,64]: 16-row LDS tile, 4 rows/wave, no shfl ---
__global__ __launch_bounds__(256) void k_xw(const float* __restrict__ x,
                                            const float* __restrict__ W1,
                                            float* __restrict__ xw, int N) {
    __shared__ float  w1l[128 * 64];   // 32 KB
    __shared__ float4 xt[16][32];      // 8 KB: 16 rows x 128 floats
    for (int t = threadIdx.x; t < 128 * 64; t += 256) w1l[t] = W1[t];
    int lane = threadIdx.x & 63;
    int wv   = threadIdx.x >> 6;
    for (int base = blockIdx.x * 16; base < N; base += gridDim.x * 16) {
        __syncthreads();   // also covers w1l staging on first pass
        for (int t = threadIdx.x; t < 16 * 32; t += 256)
            ((float4*)xt)[t] = ((const float4*)x)[(size_t)base * 32 + t];
        __syncthreads();
        int r0 = wv * 4;
        float a0 = 0.f, a1 = 0.f, a2 = 0.f, a3 = 0.f;
#pragma unroll
        for (int q = 0; q < 32; ++q) {
            float4 x0 = xt[r0][q], x1 = xt[r0 + 1][q], x2 = xt[r0 + 2][q], x3 = xt[r0 + 3][q];
            float wa = w1l[(4 * q + 0) * 64 + lane];
            float wb = w1l[(4 * q + 1) * 64 + lane];
            float wc = w1l[(4 * q + 2) * 64 + lane];
            float wd = w1l[(4 * q + 3) * 64 + lane];
            a0 = fmaf(x0.x, wa, a0); a0 = fmaf(x0.y, wb, a0); a0 = fmaf(x0.z, wc, a0); a0 = fmaf(x0.w, wd, a0);
            a1 = fmaf(x1.x, wa, a1); a1 = fmaf(x1.y, wb, a1); a1 = fmaf(x1.z, wc, a1); a1 = fmaf(x1.w, wd, a1);
            a2 = fmaf(x2.x, wa, a2); a2 = fmaf(x2.y, wb, a2); a2 = fmaf(x2.z, wc, a2); a2 = fmaf(x2.w, wd, a2);
            a3 = fmaf(x3.x, wa, a3); a3 = fmaf(x3.y, wb, a3); a3 = fmaf(x3.z, wc, a3); a3 = fmaf(x3.w, wd, a3);
        }
        int gr = base + r0;
        xw[(size_t)(gr + 0) * 64 + lane] = a0;
        xw[(size_t)(gr + 1) * 64 + lane] = a1;
        xw[(size_t)(gr + 2) * 64 + lane] = a2;
        xw[(size_t)(gr + 3) * 64 + lane] = a3;
    }
}

// ---- counting-sort edges into per-target buckets: (r, norm) -----------------
__global__ void k_bucket(const int* __restrict__ ei, const float* __restrict__ ew,
                         const float* __restrict__ dis, const int* __restrict__ offs,
                         int* __restrict__ cursor, int2* __restrict__ bucket, int E) {
    int e = blockIdx.x * blockDim.x + threadIdx.x;
    if (e < E) {
        int r = ei[e], c = ei[E + e];
        float norm = dis[r] * ew[e] * dis[c];
        int pos = offs[c] + atomicAdd(&cursor[c], 1);
        bucket[pos] = make_int2(r, __float_as_int(norm));
    }
}

// ---- per-row gather (float4-wide, 4 edges in parallel): ---------------------
// h[c,:] = relu(sum_e xw[r_e,:]*norm_e + self + b1)
// lane = (sub, q): sub=lane>>4 picks edge-in-quad, q=lane&15 picks float4 block.
__global__ __launch_bounds__(256) void k_gather(const int* __restrict__ offs,
                         const int2* __restrict__ bucket,
                         const float* __restrict__ xw, const float* __restrict__ dis,
                         const float* __restrict__ b1, float* __restrict__ h, int N) {
    int lane = threadIdx.x & 63;
    int sub = lane >> 4, q = lane & 15;
    int wid  = blockIdx.x * 4 + (threadIdx.x >> 6);
    int nw   = 4 * gridDim.x;
    const float4* xw4 = (const float4*)xw;
    for (int c = wid; c < N; c += nw) {
        int beg = offs[c], end = offs[c + 1];
        float d = dis[c];
        float4 a0 = make_float4(0.f, 0.f, 0.f, 0.f), a1 = a0;
        for (int i = beg; i < end; i += 64) {
            int nloc = min(64, end - i);
            int2 b = (i + lane < end) ? bucket[i + lane] : make_int2(0, 0);
            int rv = b.x;
            float nv = __int_as_float(b.y);   // padded lanes carry norm = 0
            int jmax = (nloc + 3) >> 2;
            for (int j = 0; j < jmax; ++j) {
                int e = 4 * j + sub;          // <= 63 always
                int   r  = __shfl(rv, e);
                float nm = __shfl(nv, e);
                float4 v = xw4[(size_t)r * 16 + q];
                if (j & 1) {
                    a1.x = fmaf(v.x, nm, a1.x); a1.y = fmaf(v.y, nm, a1.y);
                    a1.z = fmaf(v.z, nm, a1.z); a1.w = fmaf(v.w, nm, a1.w);
                } else {
                    a0.x = fmaf(v.x, nm, a0.x); a0.y = fmaf(v.y, nm, a0.y);
                    a0.z = fmaf(v.z, nm, a0.z); a0.w = fmaf(v.w, nm, a0.w);
                }
            }
        }
        a0.x += a1.x; a0.y += a1.y; a0.z += a1.z; a0.w += a1.w;
        // fold the 4 sub-partials
        a0.x += __shfl_xor(a0.x, 16); a0.y += __shfl_xor(a0.y, 16);
        a0.z += __shfl_xor(a0.z, 16); a0.w += __shfl_xor(a0.w, 16);
        a0.x += __shfl_xor(a0.x, 32); a0.y += __shfl_xor(a0.y, 32);
        a0.z += __shfl_xor(a0.z, 32); a0.w += __shfl_xor(a0.w, 32);
        float4 self = xw4[(size_t)c * 16 + q];
        float4 bb = ((const float4*)b1)[q];
        float dd = d * d;
        float4 v;
        v.x = a0.x + self.x * dd + bb.x; v.y = a0.y + self.y * dd + bb.y;
        v.z = a0.z + self.z * dd + bb.z; v.w = a0.w + self.w * dd + bb.w;
        v.x = v.x > 0.f ? v.x : 0.f; v.y = v.y > 0.f ? v.y : 0.f;
        v.z = v.z > 0.f ? v.z : 0.f; v.w = v.w > 0.f ? v.w : 0.f;
        if (sub == 0) ((float4*)h)[(size_t)c * 16 + q] = v;
    }
}

// ---- s = softmax((h@Wm1+bm1)@Wm2+bm2): 16-row tile, 4 rows/wave -------------
__global__ __launch_bounds__(256) void k_mlp(const float* __restrict__ h,
                      const float* __restrict__ Wm1, const float* __restrict__ bm1,
                      const float* __restrict__ Wm2, const float* __restrict__ bm2,
                      float* __restrict__ s, int N) {
    __shared__ float  w1l[4096], w2l[4096], b1l[64], b2l[64];
    __shared__ float4 ht[16][16];      // 4 KB
    __shared__ float  tt[4][4][64];    // 4 KB per-wave layer-1 scratch
    for (int t = threadIdx.x; t < 4096; t += 256) {
        w1l[t] = Wm1[t];
        w2l[t] = Wm2[t];
    }
    if (threadIdx.x < 64) {
        b1l[threadIdx.x] = bm1[threadIdx.x];
        b2l[threadIdx.x] = bm2[threadIdx.x];
    }
    int lane = threadIdx.x & 63;
    int wv   = threadIdx.x >> 6;
    for (int base = blockIdx.x * 16; base < N; base += gridDim.x * 16) {
        __syncthreads();
        for (int t = threadIdx.x; t < 16 * 16; t += 256)
            ((float4*)ht)[t] = ((const float4*)h)[(size_t)base * 16 + t];
        __syncthreads();
        int r0 = wv * 4;
        float t0 = b1l[lane], t1 = t0, t2 = t0, t3 = t0;
#pragma unroll
        for (int q = 0; q < 16; ++q) {
            float4 h0 = ht[r0][q], h1 = ht[r0 + 1][q], h2 = ht[r0 + 2][q], h3 = ht[r0 + 3][q];
            float wa = w1l[(4 * q + 0) * 64 + lane];
            float wb = w1l[(4 * q + 1) * 64 + lane];
            float wc = w1l[(4 * q + 2) * 64 + lane];
            float wd = w1l[(4 * q + 3) * 64 + lane];
            t0 = fmaf(h0.x, wa, t0); t0 = fmaf(h0.y, wb, t0); t0 = fmaf(h0.z, wc, t0); t0 = fmaf(h0.w, wd, t0);
            t1 = fmaf(h1.x, wa, t1); t1 = fmaf(h1.y, wb, t1); t1 = fmaf(h1.z, wc, t1); t1 = fmaf(h1.w, wd, t1);
            t2 = fmaf(h2.x, wa, t2); t2 = fmaf(h2.y, wb, t2); t2 = fmaf(h2.z, wc, t2); t2 = fmaf(h2.w, wd, t2);
            t3 = fmaf(h3.x, wa, t3); t3 = fmaf(h3.y, wb, t3); t3 = fmaf(h3.z, wc, t3); t3 = fmaf(h3.w, wd, t3);
        }
        tt[wv][0][lane] = t0; tt[wv][1][lane] = t1;
        tt[wv][2][lane] = t2; tt[wv][3][lane] = t3;
        __syncthreads();
        float g0 = b2l[lane], g1 = g0, g2 = g0, g3 = g0;
#pragma unroll
        for (int q = 0; q < 16; ++q) {
            float4 u0 = ((float4*)tt[wv][0])[q], u1 = ((float4*)tt[wv][1])[q];
            float4 u2 = ((float4*)tt[wv][2])[q], u3 = ((float4*)tt[wv][3])[q];
            float wa = w2l[(4 * q + 0) * 64 + lane];
            float wb = w2l[(4 * q + 1) * 64 + lane];
            float wc = w2l[(4 * q + 2) * 64 + lane];
            float wd = w2l[(4 * q + 3) * 64 + lane];
            g0 = fmaf(u0.x, wa, g0); g0 = fmaf(u0.y, wb, g0); g0 = fmaf(u0.z, wc, g0); g0 = fmaf(u0.w, wd, g0);
            g1 = fmaf(u1.x, wa, g1); g1 = fmaf(u1.y, wb, g1); g1 = fmaf(u1.z, wc, g1); g1 = fmaf(u1.w, wd, g1);
            g2 = fmaf(u2.x, wa, g2); g2 = fmaf(u2.y, wb, g2); g2 = fmaf(u2.z, wc, g2); g2 = fmaf(u2.w, wd, g2);
            g3 = fmaf(u3.x, wa, g3); g3 = fmaf(u3.y, wb, g3); g3 = fmaf(u3.z, wc, g3); g3 = fmaf(u3.w, wd, g3);
        }
        float m0 = g0, m1 = g1, m2 = g2, m3 = g3;
#pragma unroll
        for (int o = 32; o > 0; o >>= 1) {
            m0 = fmaxf(m0, __shfl_xor(m0, o));
            m1 = fmaxf(m1, __shfl_xor(m1, o));
            m2 = fmaxf(m2, __shfl_xor(m2, o));
            m3 = fmaxf(m3, __shfl_xor(m3, o));
        }
        float e0 = __expf(g0 - m0), e1 = __expf(g1 - m1);
        float e2 = __expf(g2 - m2), e3 = __expf(g3 - m3);
        float s0 = e0, s1 = e1, s2 = e2, s3 = e3;
#pragma unroll
        for (int o = 32; o > 0; o >>= 1) {
            s0 += __shfl_xor(s0, o);
            s1 += __shfl_xor(s1, o);
            s2 += __shfl_xor(s2, o);
            s3 += __shfl_xor(s3, o);
        }
        int gr = base + r0;
        s[(size_t)(gr + 0) * 64 + lane] = e0 / s0;
        s[(size_t)(gr + 1) * 64 + lane] = e1 / s1;
        s[(size_t)(gr + 2) * 64 + lane] = e2 / s2;
        s[(size_t)(gr + 3) * 64 + lane] = e3 / s3;
    }
}

// ---- row reductions via 64-row LDS tile: ss=s^T s, cs=colsum(s), ca=s^T deg -
__global__ __launch_bounds__(256) void k_rowred(const float* __restrict__ s,
                         const int* __restrict__ cnt,
                         float* __restrict__ ssg, float* __restrict__ cag,
                         float* __restrict__ csg, int N) {
    __shared__ float tile[64][64];   // 16 KB
    int lane = threadIdx.x & 63;
    int wv   = threadIdx.x >> 6;
    int base = blockIdx.x * 64;
    if (base >= N) return;
    for (int t = threadIdx.x; t < 1024; t += 256)
        ((float4*)tile)[t] = ((const float4*)(s + (size_t)base * 64))[t];
    __syncthreads();
    float acc[16];
#pragma unroll
    for (int i = 0; i < 16; ++i) acc[i] = 0.f;
    for (int r = 0; r < 64; ++r) {
        float sj = tile[r][lane];
        const float* brow = &tile[r][wv * 16];
#pragma unroll
        for (int i = 0; i < 16; ++i) acc[i] = fmaf(brow[i], sj, acc[i]);
    }
    float csj = 0.f, caj = 0.f;
#pragma unroll
    for (int i = 0; i < 16; ++i) {
        int r = wv * 16 + i;
        float sj = tile[r][lane];
        csj += sj;
        caj = fmaf(sj, (float)cnt[base + r], caj);
    }
#pragma unroll
    for (int i = 0; i < 16; ++i) atomicAdd(&ssg[(wv * 16 + i) * 64 + lane], acc[i]);
    atomicAdd(&csg[lane], csj);
    atomicAdd(&cag[lane], caj);
}

// ---- trace via buckets (float4-wide, 4 edges parallel): ---------------------
// tr += dot(sum_e s[r_e,:], s[c,:]) per row c
__global__ __launch_bounds__(256) void k_trace2(const int* __restrict__ offs,
                         const int2* __restrict__ bucket,
                         const float* __restrict__ s, float* __restrict__ traceg, int N) {
    int lane = threadIdx.x & 63;
    int sub = lane >> 4, q = lane & 15;
    int wid  = blockIdx.x * 4 + (threadIdx.x >> 6);
    int nw   = 4 * gridDim.x;
    const float4* s4 = (const float4*)s;
    float tacc = 0.f;
    for (int c = wid; c < N; c += nw) {
        int beg = offs[c], end = offs[c + 1];
        float4 sc = s4[(size_t)c * 16 + q];
        float4 a0 = make_float4(0.f, 0.f, 0.f, 0.f), a1 = a0;
        for (int i = beg; i < end; i += 64) {
            int nloc = min(64, end - i);
            int rv = (i + lane < end) ? bucket[i + lane].x : 0;
            int jmax = (nloc + 3) >> 2;
            for (int j = 0; j < jmax; ++j) {
                int e = 4 * j + sub;          // <= 63 always
                int r = __shfl(rv, e);
                float m = (e < nloc) ? 1.f : 0.f;
                float4 v = s4[(size_t)r * 16 + q];
                if (j & 1) {
                    a1.x = fmaf(v.x, m, a1.x); a1.y = fmaf(v.y, m, a1.y);
                    a1.z = fmaf(v.z, m, a1.z); a1.w = fmaf(v.w, m, a1.w);
                } else {
                    a0.x = fmaf(v.x, m, a0.x); a0.y = fmaf(v.y, m, a0.y);
                    a0.z = fmaf(v.z, m, a0.z); a0.w = fmaf(v.w, m, a0.w);
                }
            }
        }
        a0.x += a1.x; a0.y += a1.y; a0.z += a1.z; a0.w += a1.w;
        a0.x += __shfl_xor(a0.x, 16); a0.y += __shfl_xor(a0.y, 16);
        a0.z += __shfl_xor(a0.z, 16); a0.w += __shfl_xor(a0.w, 16);
        a0.x += __shfl_xor(a0.x, 32); a0.y += __shfl_xor(a0.y, 32);
        a0.z += __shfl_xor(a0.z, 32); a0.w += __shfl_xor(a0.w, 32);
        tacc += a0.x * sc.x + a0.y * sc.y + a0.z * sc.z + a0.w * sc.w;
    }
    tacc *= 0.25f;   // each q-partial replicated across 4 subs
#pragma unroll
    for (int o = 32; o > 0; o >>= 1) tacc += __shfl_xor(tacc, o);
    __shared__ float bsum;
    if (threadIdx.x == 0) bsum = 0.f;
    __syncthreads();
    if (lane == 0) atomicAdd(&bsum, tacc);
    __syncthreads();
    if (threadIdx.x == 0) atomicAdd(traceg, bsum);
}

// ---- finalize: spectral + ortho + cluster loss ------------------------------
__global__ void k_final(const float* __restrict__ ssg, const float* __restrict__ cag,
                        const float* __restrict__ csg, const float* __restrict__ traceg,
                        float Ef, float Nf, float* __restrict__ out) {
    __shared__ float red[256];
    int tid = threadIdx.x;

    float a = 0.f;
    for (int t = tid; t < 4096; t += 256) { float v = ssg[t]; a += v * v; }
    red[tid] = a; __syncthreads();
    for (int o = 128; o > 0; o >>= 1) { if (tid < o) red[tid] += red[tid + o]; __syncthreads(); }
    float ss_sumsq = red[0]; __syncthreads();

    a = (tid < 64) ? ssg[tid * 64 + tid] : 0.f;
    red[tid] = a; __syncthreads();
    for (int o = 128; o > 0; o >>= 1) { if (tid < o) red[tid] += red[tid + o]; __syncthreads(); }
    float tr_ss = red[0]; __syncthreads();

    a = (tid < 64) ? cag[tid] * cag[tid] : 0.f;
    red[tid] = a; __syncthreads();
    for (int o = 128; o > 0; o >>= 1) { if (tid < o) red[tid] += red[tid + o]; __syncthreads(); }
    float ca_ss = red[0]; __syncthreads();

    a = (tid < 64) ? csg[tid] * csg[tid] : 0.f;
    red[tid] = a; __syncthreads();
    for (int o = 128; o > 0; o >>= 1) { if (tid < o) red[tid] += red[tid + o]; __syncthreads(); }
    float cs_ss = red[0];

    if (tid == 0) {
        // 2m = deg.sum() = E
        float spec = -(traceg[0] - ca_ss / Ef) / Ef;
        float ss_fro = sqrtf(ss_sumsq);
        // ||ss/fro - I/8||_F^2 = 1 - tr(ss)/(4*fro) + 1
        float ortho = sqrtf(fmaxf(2.f - tr_ss / (4.f * ss_fro), 0.f));
        float clus = sqrtf(cs_ss) / Nf * 8.f - 1.f;
        out[0] = spec + ortho + clus;
    }
}

extern "C" void kernel_launch(void* const* d_in, const int* in_sizes, int n_in,
                              void* d_out, int out_size, void* d_ws, size_t ws_size,
                              hipStream_t stream) {
    const float* x   = (const float*)d_in[0];
    const int*   ei  = (const int*)d_in[1];
    const float* ew  = (const float*)d_in[2];
    const float* W1  = (const float*)d_in[3];
    const float* b1  = (const float*)d_in[4];
    const float* Wm1 = (const float*)d_in[5];
    const float* bm1 = (const float*)d_in[6];
    const float* Wm2 = (const float*)d_in[7];
    const float* bm2 = (const float*)d_in[8];
    float* out = (float*)d_out;

    const int N = in_sizes[0] / 128;   // 16384
    const int E = in_sizes[2];         // 524288

    float* ws = (float*)d_ws;
    // --- zeroed region ---
    float* deg    = ws;                       // N  (-> dis in place after k_scan)
    int*   cnt    = (int*)(ws + N);           // N
    int*   cursor = cnt + N;                  // N
    float* ssg    = (float*)(cursor + N);     // 4096
    float* cag    = ssg + 4096;               // 64
    float* csg    = cag + 64;                 // 64
    float* trg    = csg + 64;                 // 1
    size_t zf = (size_t)3 * N + 4096 + 64 + 64 + 1;
    // --- uninitialized region (16B-aligned for float4 access) ---
    size_t xoff = (zf + 3) & ~(size_t)3;
    float* xw = ws + xoff;                    // N*64
    float* h  = xw + (size_t)N * 64;          // N*64
    size_t foff = xoff + (size_t)2 * N * 64;
    int2* bucket = (int2*)(ws + foff);        // E int2
    int*  offs   = (int*)(bucket + E);        // N+1
    float* sbuf  = out;                       // s lives in d_out (f32 output 0)

    hipMemsetAsync(d_ws, 0, zf * sizeof(float), stream);

    k_deg<<<(E + 255) / 256, 256, 0, stream>>>(ei, ew, deg, cnt, E);
    k_scan<<<1, 1024, 0, stream>>>(cnt, offs, deg, N);
    k_xw<<<512, 256, 0, stream>>>(x, W1, xw, N);
    k_bucket<<<(E + 255) / 256, 256, 0, stream>>>(ei, ew, deg, offs, cursor, bucket, E);
    k_gather<<<4096, 256, 0, stream>>>(offs, bucket, xw, deg, b1, h, N);
    k_mlp<<<512, 256, 0, stream>>>(h, Wm1, bm1, Wm2, bm2, sbuf, N);
    k_rowred<<<(N + 63) / 64, 256, 0, stream>>>(sbuf, cnt, ssg, cag, csg, N);
    k_trace2<<<4096, 256, 0, stream>>>(offs, bucket, sbuf, trg, N);
    k_final<<<1, 256, 0, stream>>>(ssg, cag, csg, trg, (float)E, (float)N, out + (size_t)N * 64);
}

// Round 7
// 305.866 us; speedup vs baseline: 1.9023x; 1.0215x over previous
//
#include <hip/hip_runtime.h>
#include <hip/hip_bf16.h>

// ---- degrees: deg[c] += w_e (gcn) ; cnt[c] += 1 (dmon + bucket sizes) -------
__global__ void k_deg(const int* __restrict__ ei, const float* __restrict__ ew,
                      float* __restrict__ deg, int* __restrict__ cnt, int E) {
    int e = blockIdx.x * blockDim.x + threadIdx.x;
    if (e < E) {
        int c = ei[E + e];
        atomicAdd(deg + c, ew[e]);
        atomicAdd(cnt + c, 1);
    }
}

// ---- exclusive prefix sum of cnt -> offs[0..N]; fused dis = rsqrt(deg+1) ----
__global__ void k_scan(const int* __restrict__ cnt, int* __restrict__ offs,
                       float* __restrict__ deg, int N) {
    __shared__ int part[1024];
    int tid = threadIdx.x;
    int C = (N + 1023) / 1024;   // 16 for N=16384
    int base = tid * C;
    int loc[16];
    int sum = 0;
#pragma unroll
    for (int i = 0; i < 16; ++i) {
        if (i < C) {
            int idx = base + i;
            loc[i] = sum;
            sum += (idx < N) ? cnt[idx] : 0;
        }
    }
    part[tid] = sum;
    __syncthreads();
    for (int o = 1; o < 1024; o <<= 1) {
        int t = (tid >= o) ? part[tid - o] : 0;
        __syncthreads();
        part[tid] += t;
        __syncthreads();
    }
    int excl = part[tid] - sum;
#pragma unroll
    for (int i = 0; i < 16; ++i) {
        if (i < C) {
            int idx = base + i;
            if (idx < N) offs[idx] = excl + loc[i];
        }
    }
    if (tid == 1023) offs[N] = part[tid];
    for (int i = tid; i < N; i += 1024) deg[i] = rsqrtf(deg[i] + 1.0f);
}

// ---- xw = x @ W1  [N,128]x[128,64]: 16-row LDS tile, 4 rows/wave, no shfl ---
__global__ __launch_bounds__(256) void k_xw(const float* __restrict__ x,
                                            const float* __restrict__ W1,
                                            float* __restrict__ xw, int N) {
    __shared__ float  w1l[128 * 64];   // 32 KB
    __shared__ float4 xt[16][32];      // 8 KB: 16 rows x 128 floats
    for (int t = threadIdx.x; t < 128 * 64; t += 256) w1l[t] = W1[t];
    int lane = threadIdx.x & 63;
    int wv   = threadIdx.x >> 6;
    for (int base = blockIdx.x * 16; base < N; base += gridDim.x * 16) {
        __syncthreads();   // also covers w1l staging on first pass
        for (int t = threadIdx.x; t < 16 * 32; t += 256)
            ((float4*)xt)[t] = ((const float4*)x)[(size_t)base * 32 + t];
        __syncthreads();
        int r0 = wv * 4;
        float a0 = 0.f, a1 = 0.f, a2 = 0.f, a3 = 0.f;
#pragma unroll
        for (int q = 0; q < 32; ++q) {
            float4 x0 = xt[r0][q], x1 = xt[r0 + 1][q], x2 = xt[r0 + 2][q], x3 = xt[r0 + 3][q];
            float wa = w1l[(4 * q + 0) * 64 + lane];
            float wb = w1l[(4 * q + 1) * 64 + lane];
            float wc = w1l[(4 * q + 2) * 64 + lane];
            float wd = w1l[(4 * q + 3) * 64 + lane];
            a0 = fmaf(x0.x, wa, a0); a0 = fmaf(x0.y, wb, a0); a0 = fmaf(x0.z, wc, a0); a0 = fmaf(x0.w, wd, a0);
            a1 = fmaf(x1.x, wa, a1); a1 = fmaf(x1.y, wb, a1); a1 = fmaf(x1.z, wc, a1); a1 = fmaf(x1.w, wd, a1);
            a2 = fmaf(x2.x, wa, a2); a2 = fmaf(x2.y, wb, a2); a2 = fmaf(x2.z, wc, a2); a2 = fmaf(x2.w, wd, a2);
            a3 = fmaf(x3.x, wa, a3); a3 = fmaf(x3.y, wb, a3); a3 = fmaf(x3.z, wc, a3); a3 = fmaf(x3.w, wd, a3);
        }
        int gr = base + r0;
        xw[(size_t)(gr + 0) * 64 + lane] = a0;
        xw[(size_t)(gr + 1) * 64 + lane] = a1;
        xw[(size_t)(gr + 2) * 64 + lane] = a2;
        xw[(size_t)(gr + 3) * 64 + lane] = a3;
    }
}

// ---- counting-sort edges into per-target buckets: (r, norm) -----------------
__global__ void k_bucket(const int* __restrict__ ei, const float* __restrict__ ew,
                         const float* __restrict__ dis, const int* __restrict__ offs,
                         int* __restrict__ cursor, int2* __restrict__ bucket, int E) {
    int e = blockIdx.x * blockDim.x + threadIdx.x;
    if (e < E) {
        int r = ei[e], c = ei[E + e];
        float norm = dis[r] * ew[e] * dis[c];
        int pos = offs[c] + atomicAdd(&cursor[c], 1);
        bucket[pos] = make_int2(r, __float_as_int(norm));
    }
}

// ---- per-row gather (float4-wide, 4 edges parallel, 4-deep load batches): ---
// h[c,:] = relu(sum_e xw[r_e,:]*norm_e + self + b1)
__global__ __launch_bounds__(256) void k_gather(const int* __restrict__ offs,
                         const int2* __restrict__ bucket,
                         const float* __restrict__ xw, const float* __restrict__ dis,
                         const float* __restrict__ b1, float* __restrict__ h, int N) {
    int lane = threadIdx.x & 63;
    int sub = lane >> 4, q = lane & 15;
    int wid  = blockIdx.x * 4 + (threadIdx.x >> 6);
    int nw   = 4 * gridDim.x;
    const float4* xw4 = (const float4*)xw;
    for (int c = wid; c < N; c += nw) {
        int beg = offs[c], end = offs[c + 1];
        float d = dis[c];
        float4 acc0 = make_float4(0.f, 0.f, 0.f, 0.f);
        float4 acc1 = acc0, acc2 = acc0, acc3 = acc0;
        for (int i = beg; i < end; i += 64) {
            int nloc = min(64, end - i);
            int2 b = (i + lane < end) ? bucket[i + lane] : make_int2(0, 0);
            int rv = b.x;
            float nv = __int_as_float(b.y);   // padded lanes carry norm = 0
            int jmax = (nloc + 3) >> 2;
            int j = 0;
            for (; j + 4 <= jmax; j += 4) {   // 16 edges: 4 independent load chains
                int e0 = 4 * j + sub;
                int   r0 = __shfl(rv, e0),      r1 = __shfl(rv, e0 + 4);
                int   r2 = __shfl(rv, e0 + 8),  r3 = __shfl(rv, e0 + 12);
                float n0 = __shfl(nv, e0),      n1 = __shfl(nv, e0 + 4);
                float n2 = __shfl(nv, e0 + 8),  n3 = __shfl(nv, e0 + 12);
                float4 v0 = xw4[(size_t)r0 * 16 + q];
                float4 v1 = xw4[(size_t)r1 * 16 + q];
                float4 v2 = xw4[(size_t)r2 * 16 + q];
                float4 v3 = xw4[(size_t)r3 * 16 + q];
                acc0.x = fmaf(v0.x, n0, acc0.x); acc0.y = fmaf(v0.y, n0, acc0.y);
                acc0.z = fmaf(v0.z, n0, acc0.z); acc0.w = fmaf(v0.w, n0, acc0.w);
                acc1.x = fmaf(v1.x, n1, acc1.x); acc1.y = fmaf(v1.y, n1, acc1.y);
                acc1.z = fmaf(v1.z, n1, acc1.z); acc1.w = fmaf(v1.w, n1, acc1.w);
                acc2.x = fmaf(v2.x, n2, acc2.x); acc2.y = fmaf(v2.y, n2, acc2.y);
                acc2.z = fmaf(v2.z, n2, acc2.z); acc2.w = fmaf(v2.w, n2, acc2.w);
                acc3.x = fmaf(v3.x, n3, acc3.x); acc3.y = fmaf(v3.y, n3, acc3.y);
                acc3.z = fmaf(v3.z, n3, acc3.z); acc3.w = fmaf(v3.w, n3, acc3.w);
            }
            for (; j < jmax; ++j) {
                int e = 4 * j + sub;
                int   r  = __shfl(rv, e);
                float nm = __shfl(nv, e);
                float4 v = xw4[(size_t)r * 16 + q];
                acc0.x = fmaf(v.x, nm, acc0.x); acc0.y = fmaf(v.y, nm, acc0.y);
                acc0.z = fmaf(v.z, nm, acc0.z); acc0.w = fmaf(v.w, nm, acc0.w);
            }
        }
        acc0.x += acc1.x + acc2.x + acc3.x; acc0.y += acc1.y + acc2.y + acc3.y;
        acc0.z += acc1.z + acc2.z + acc3.z; acc0.w += acc1.w + acc2.w + acc3.w;
        acc0.x += __shfl_xor(acc0.x, 16); acc0.y += __shfl_xor(acc0.y, 16);
        acc0.z += __shfl_xor(acc0.z, 16); acc0.w += __shfl_xor(acc0.w, 16);
        acc0.x += __shfl_xor(acc0.x, 32); acc0.y += __shfl_xor(acc0.y, 32);
        acc0.z += __shfl_xor(acc0.z, 32); acc0.w += __shfl_xor(acc0.w, 32);
        float4 self = xw4[(size_t)c * 16 + q];
        float4 bb = ((const float4*)b1)[q];
        float dd = d * d;
        float4 v;
        v.x = acc0.x + self.x * dd + bb.x; v.y = acc0.y + self.y * dd + bb.y;
        v.z = acc0.z + self.z * dd + bb.z; v.w = acc0.w + self.w * dd + bb.w;
        v.x = v.x > 0.f ? v.x : 0.f; v.y = v.y > 0.f ? v.y : 0.f;
        v.z = v.z > 0.f ? v.z : 0.f; v.w = v.w > 0.f ? v.w : 0.f;
        if (sub == 0) ((float4*)h)[(size_t)c * 16 + q] = v;
    }
}

// ---- s = softmax((h@Wm1+bm1)@Wm2+bm2): 16-row tile, 4 rows/wave -------------
__global__ __launch_bounds__(256) void k_mlp(const float* __restrict__ h,
                      const float* __restrict__ Wm1, const float* __restrict__ bm1,
                      const float* __restrict__ Wm2, const float* __restrict__ bm2,
                      float* __restrict__ s, int N) {
    __shared__ float  w1l[4096], w2l[4096], b1l[64], b2l[64];
    __shared__ float4 ht[16][16];      // 4 KB
    __shared__ float  tt[4][4][64];    // 4 KB per-wave layer-1 scratch
    for (int t = threadIdx.x; t < 4096; t += 256) {
        w1l[t] = Wm1[t];
        w2l[t] = Wm2[t];
    }
    if (threadIdx.x < 64) {
        b1l[threadIdx.x] = bm1[threadIdx.x];
        b2l[threadIdx.x] = bm2[threadIdx.x];
    }
    int lane = threadIdx.x & 63;
    int wv   = threadIdx.x >> 6;
    for (int base = blockIdx.x * 16; base < N; base += gridDim.x * 16) {
        __syncthreads();
        for (int t = threadIdx.x; t < 16 * 16; t += 256)
            ((float4*)ht)[t] = ((const float4*)h)[(size_t)base * 16 + t];
        __syncthreads();
        int r0 = wv * 4;
        float t0 = b1l[lane], t1 = t0, t2 = t0, t3 = t0;
#pragma unroll
        for (int q = 0; q < 16; ++q) {
            float4 h0 = ht[r0][q], h1 = ht[r0 + 1][q], h2 = ht[r0 + 2][q], h3 = ht[r0 + 3][q];
            float wa = w1l[(4 * q + 0) * 64 + lane];
            float wb = w1l[(4 * q + 1) * 64 + lane];
            float wc = w1l[(4 * q + 2) * 64 + lane];
            float wd = w1l[(4 * q + 3) * 64 + lane];
            t0 = fmaf(h0.x, wa, t0); t0 = fmaf(h0.y, wb, t0); t0 = fmaf(h0.z, wc, t0); t0 = fmaf(h0.w, wd, t0);
            t1 = fmaf(h1.x, wa, t1); t1 = fmaf(h1.y, wb, t1); t1 = fmaf(h1.z, wc, t1); t1 = fmaf(h1.w, wd, t1);
            t2 = fmaf(h2.x, wa, t2); t2 = fmaf(h2.y, wb, t2); t2 = fmaf(h2.z, wc, t2); t2 = fmaf(h2.w, wd, t2);
            t3 = fmaf(h3.x, wa, t3); t3 = fmaf(h3.y, wb, t3); t3 = fmaf(h3.z, wc, t3); t3 = fmaf(h3.w, wd, t3);
        }
        tt[wv][0][lane] = t0; tt[wv][1][lane] = t1;
        tt[wv][2][lane] = t2; tt[wv][3][lane] = t3;
        __syncthreads();
        float g0 = b2l[lane], g1 = g0, g2 = g0, g3 = g0;
#pragma unroll
        for (int q = 0; q < 16; ++q) {
            float4 u0 = ((float4*)tt[wv][0])[q], u1 = ((float4*)tt[wv][1])[q];
            float4 u2 = ((float4*)tt[wv][2])[q], u3 = ((float4*)tt[wv][3])[q];
            float wa = w2l[(4 * q + 0) * 64 + lane];
            float wb = w2l[(4 * q + 1) * 64 + lane];
            float wc = w2l[(4 * q + 2) * 64 + lane];
            float wd = w2l[(4 * q + 3) * 64 + lane];
            g0 = fmaf(u0.x, wa, g0); g0 = fmaf(u0.y, wb, g0); g0 = fmaf(u0.z, wc, g0); g0 = fmaf(u0.w, wd, g0);
            g1 = fmaf(u1.x, wa, g1); g1 = fmaf(u1.y, wb, g1); g1 = fmaf(u1.z, wc, g1); g1 = fmaf(u1.w, wd, g1);
            g2 = fmaf(u2.x, wa, g2); g2 = fmaf(u2.y, wb, g2); g2 = fmaf(u2.z, wc, g2); g2 = fmaf(u2.w, wd, g2);
            g3 = fmaf(u3.x, wa, g3); g3 = fmaf(u3.y, wb, g3); g3 = fmaf(u3.z, wc, g3); g3 = fmaf(u3.w, wd, g3);
        }
        float m0 = g0, m1 = g1, m2 = g2, m3 = g3;
#pragma unroll
        for (int o = 32; o > 0; o >>= 1) {
            m0 = fmaxf(m0, __shfl_xor(m0, o));
            m1 = fmaxf(m1, __shfl_xor(m1, o));
            m2 = fmaxf(m2, __shfl_xor(m2, o));
            m3 = fmaxf(m3, __shfl_xor(m3, o));
        }
        float e0 = __expf(g0 - m0), e1 = __expf(g1 - m1);
        float e2 = __expf(g2 - m2), e3 = __expf(g3 - m3);
        float s0 = e0, s1 = e1, s2 = e2, s3 = e3;
#pragma unroll
        for (int o = 32; o > 0; o >>= 1) {
            s0 += __shfl_xor(s0, o);
            s1 += __shfl_xor(s1, o);
            s2 += __shfl_xor(s2, o);
            s3 += __shfl_xor(s3, o);
        }
        int gr = base + r0;
        s[(size_t)(gr + 0) * 64 + lane] = e0 / s0;
        s[(size_t)(gr + 1) * 64 + lane] = e1 / s1;
        s[(size_t)(gr + 2) * 64 + lane] = e2 / s2;
        s[(size_t)(gr + 3) * 64 + lane] = e3 / s3;
    }
}

// ---- row reductions via 64-row LDS tile: ss=s^T s, cs=colsum(s), ca=s^T deg -
__global__ __launch_bounds__(256) void k_rowred(const float* __restrict__ s,
                         const int* __restrict__ cnt,
                         float* __restrict__ ssg, float* __restrict__ cag,
                         float* __restrict__ csg, int N) {
    __shared__ float tile[64][64];   // 16 KB
    int lane = threadIdx.x & 63;
    int wv   = threadIdx.x >> 6;
    int base = blockIdx.x * 64;
    if (base >= N) return;
    for (int t = threadIdx.x; t < 1024; t += 256)
        ((float4*)tile)[t] = ((const float4*)(s + (size_t)base * 64))[t];
    __syncthreads();
    float acc[16];
#pragma unroll
    for (int i = 0; i < 16; ++i) acc[i] = 0.f;
    for (int r = 0; r < 64; ++r) {
        float sj = tile[r][lane];
        const float* brow = &tile[r][wv * 16];
#pragma unroll
        for (int i = 0; i < 16; ++i) acc[i] = fmaf(brow[i], sj, acc[i]);
    }
    float csj = 0.f, caj = 0.f;
#pragma unroll
    for (int i = 0; i < 16; ++i) {
        int r = wv * 16 + i;
        float sj = tile[r][lane];
        csj += sj;
        caj = fmaf(sj, (float)cnt[base + r], caj);
    }
#pragma unroll
    for (int i = 0; i < 16; ++i) atomicAdd(&ssg[(wv * 16 + i) * 64 + lane], acc[i]);
    atomicAdd(&csg[lane], csj);
    atomicAdd(&cag[lane], caj);
}

// ---- trace via buckets (float4-wide, 4 edges parallel, 4-deep batches): -----
// tr += dot(sum_e s[r_e,:], s[c,:]) per row c
__global__ __launch_bounds__(256) void k_trace2(const int* __restrict__ offs,
                         const int2* __restrict__ bucket,
                         const float* __restrict__ s, float* __restrict__ traceg, int N) {
    int lane = threadIdx.x & 63;
    int sub = lane >> 4, q = lane & 15;
    int wid  = blockIdx.x * 4 + (threadIdx.x >> 6);
    int nw   = 4 * gridDim.x;
    const float4* s4 = (const float4*)s;
    float tacc = 0.f;
    for (int c = wid; c < N; c += nw) {
        int beg = offs[c], end = offs[c + 1];
        float4 sc = s4[(size_t)c * 16 + q];
        float4 acc0 = make_float4(0.f, 0.f, 0.f, 0.f);
        float4 acc1 = acc0, acc2 = acc0, acc3 = acc0;
        for (int i = beg; i < end; i += 64) {
            int nloc = min(64, end - i);
            int rv = (i + lane < end) ? bucket[i + lane].x : 0;
            int jmax = (nloc + 3) >> 2;
            int j = 0;
            for (; j + 4 <= jmax; j += 4) {   // 16 edges: 4 independent load chains
                int e0 = 4 * j + sub;
                int r0 = __shfl(rv, e0),     r1 = __shfl(rv, e0 + 4);
                int r2 = __shfl(rv, e0 + 8), r3 = __shfl(rv, e0 + 12);
                float m0 = (e0      < nloc) ? 1.f : 0.f;
                float m1 = (e0 + 4  < nloc) ? 1.f : 0.f;
                float m2 = (e0 + 8  < nloc) ? 1.f : 0.f;
                float m3 = (e0 + 12 < nloc) ? 1.f : 0.f;
                float4 v0 = s4[(size_t)r0 * 16 + q];
                float4 v1 = s4[(size_t)r1 * 16 + q];
                float4 v2 = s4[(size_t)r2 * 16 + q];
                float4 v3 = s4[(size_t)r3 * 16 + q];
                acc0.x = fmaf(v0.x, m0, acc0.x); acc0.y = fmaf(v0.y, m0, acc0.y);
                acc0.z = fmaf(v0.z, m0, acc0.z); acc0.w = fmaf(v0.w, m0, acc0.w);
                acc1.x = fmaf(v1.x, m1, acc1.x); acc1.y = fmaf(v1.y, m1, acc1.y);
                acc1.z = fmaf(v1.z, m1, acc1.z); acc1.w = fmaf(v1.w, m1, acc1.w);
                acc2.x = fmaf(v2.x, m2, acc2.x); acc2.y = fmaf(v2.y, m2, acc2.y);
                acc2.z = fmaf(v2.z, m2, acc2.z); acc2.w = fmaf(v2.w, m2, acc2.w);
                acc3.x = fmaf(v3.x, m3, acc3.x); acc3.y = fmaf(v3.y, m3, acc3.y);
                acc3.z = fmaf(v3.z, m3, acc3.z); acc3.w = fmaf(v3.w, m3, acc3.w);
            }
            for (; j < jmax; ++j) {
                int e = 4 * j + sub;
                int r = __shfl(rv, e);
                float m = (e < nloc) ? 1.f : 0.f;
                float4 v = s4[(size_t)r * 16 + q];
                acc0.x = fmaf(v.x, m, acc0.x); acc0.y = fmaf(v.y, m, acc0.y);
                acc0.z = fmaf(v.z, m, acc0.z); acc0.w = fmaf(v.w, m, acc0.w);
            }
        }
        acc0.x += acc1.x + acc2.x + acc3.x; acc0.y += acc1.y + acc2.y + acc3.y;
        acc0.z += acc1.z + acc2.z + acc3.z; acc0.w += acc1.w + acc2.w + acc3.w;
        acc0.x += __shfl_xor(acc0.x, 16); acc0.y += __shfl_xor(acc0.y, 16);
        acc0.z += __shfl_xor(acc0.z, 16); acc0.w += __shfl_xor(acc0.w, 16);
        acc0.x += __shfl_xor(acc0.x, 32); acc0.y += __shfl_xor(acc0.y, 32);
        acc0.z += __shfl_xor(acc0.z, 32); acc0.w += __shfl_xor(acc0.w, 32);
        tacc += acc0.x * sc.x + acc0.y * sc.y + acc0.z * sc.z + acc0.w * sc.w;
    }
    tacc *= 0.25f;   // each q-partial replicated across 4 subs
#pragma unroll
    for (int o = 32; o > 0; o >>= 1) tacc += __shfl_xor(tacc, o);
    __shared__ float bsum;
    if (threadIdx.x == 0) bsum = 0.f;
    __syncthreads();
    if (lane == 0) atomicAdd(&bsum, tacc);
    __syncthreads();
    if (threadIdx.x == 0) atomicAdd(traceg, bsum);
}

// ---- finalize: spectral + ortho + cluster loss ------------------------------
__global__ void k_final(const float* __restrict__ ssg, const float* __restrict__ cag,
                        const float* __restrict__ csg, const float* __restrict__ traceg,
                        float Ef, float Nf, float* __restrict__ out) {
    __shared__ float red[256];
    int tid = threadIdx.x;

    float a = 0.f;
    for (int t = tid; t < 4096; t += 256) { float v = ssg[t]; a += v * v; }
    red[tid] = a; __syncthreads();
    for (int o = 128; o > 0; o >>= 1) { if (tid < o) red[tid] += red[tid + o]; __syncthreads(); }
    float ss_sumsq = red[0]; __syncthreads();

    a = (tid < 64) ? ssg[tid * 64 + tid] : 0.f;
    red[tid] = a; __syncthreads();
    for (int o = 128; o > 0; o >>= 1) { if (tid < o) red[tid] += red[tid + o]; __syncthreads(); }
    float tr_ss = red[0]; __syncthreads();

    a = (tid < 64) ? cag[tid] * cag[tid] : 0.f;
    red[tid] = a; __syncthreads();
    for (int o = 128; o > 0; o >>= 1) { if (tid < o) red[tid] += red[tid + o]; __syncthreads(); }
    float ca_ss = red[0]; __syncthreads();

    a = (tid < 64) ? csg[tid] * csg[tid] : 0.f;
    red[tid] = a; __syncthreads();
    for (int o = 128; o > 0; o >>= 1) { if (tid < o) red[tid] += red[tid + o]; __syncthreads(); }
    float cs_ss = red[0];

    if (tid == 0) {
        // 2m = deg.sum() = E
        float spec = -(traceg[0] - ca_ss / Ef) / Ef;
        float ss_fro = sqrtf(ss_sumsq);
        // ||ss/fro - I/8||_F^2 = 1 - tr(ss)/(4*fro) + 1
        float ortho = sqrtf(fmaxf(2.f - tr_ss / (4.f * ss_fro), 0.f));
        float clus = sqrtf(cs_ss) / Nf * 8.f - 1.f;
        out[0] = spec + ortho + clus;
    }
}

extern "C" void kernel_launch(void* const* d_in, const int* in_sizes, int n_in,
                              void* d_out, int out_size, void* d_ws, size_t ws_size,
                              hipStream_t stream) {
    const float* x   = (const float*)d_in[0];
    const int*   ei  = (const int*)d_in[1];
    const float* ew  = (const float*)d_in[2];
    const float* W1  = (const float*)d_in[3];
    const float* b1  = (const float*)d_in[4];
    const float* Wm1 = (const float*)d_in[5];
    const float* bm1 = (const float*)d_in[6];
    const float* Wm2 = (const float*)d_in[7];
    const float* bm2 = (const float*)d_in[8];
    float* out = (float*)d_out;

    const int N = in_sizes[0] / 128;   // 16384
    const int E = in_sizes[2];         // 524288

    float* ws = (float*)d_ws;
    // --- zeroed region ---
    float* deg    = ws;                       // N  (-> dis in place after k_scan)
    int*   cnt    = (int*)(ws + N);           // N
    int*   cursor = cnt + N;                  // N
    float* ssg    = (float*)(cursor + N);     // 4096
    float* cag    = ssg + 4096;               // 64
    float* csg    = cag + 64;                 // 64
    float* trg    = csg + 64;                 // 1
    size_t zf = (size_t)3 * N + 4096 + 64 + 64 + 1;
    // --- uninitialized region (16B-aligned for float4 access) ---
    size_t xoff = (zf + 3) & ~(size_t)3;
    float* xw = ws + xoff;                    // N*64
    float* h  = xw + (size_t)N * 64;          // N*64
    size_t foff = xoff + (size_t)2 * N * 64;
    int2* bucket = (int2*)(ws + foff);        // E int2
    int*  offs   = (int*)(bucket + E);        // N+1
    float* sbuf  = out;                       // s lives in d_out (f32 output 0)

    hipMemsetAsync(d_ws, 0, zf * sizeof(float), stream);

    k_deg<<<(E + 255) / 256, 256, 0, stream>>>(ei, ew, deg, cnt, E);
    k_scan<<<1, 1024, 0, stream>>>(cnt, offs, deg, N);
    k_xw<<<512, 256, 0, stream>>>(x, W1, xw, N);
    k_bucket<<<(E + 255) / 256, 256, 0, stream>>>(ei, ew, deg, offs, cursor, bucket, E);
    k_gather<<<4096, 256, 0, stream>>>(offs, bucket, xw, deg, b1, h, N);
    k_mlp<<<512, 256, 0, stream>>>(h, Wm1, bm1, Wm2, bm2, sbuf, N);
    k_rowred<<<(N + 63) / 64, 256, 0, stream>>>(sbuf, cnt, ssg, cag, csg, N);
    k_trace2<<<4096, 256, 0, stream>>>(offs, bucket, sbuf, trg, N);
    k_final<<<1, 256, 0, stream>>>(ssg, cag, csg, trg, (float)E, (float)N, out + (size_t)N * 64);
}